// Round 1
// baseline (3803.198 us; speedup 1.0000x reference)
//
#include <hip/hip_runtime.h>
#include <math.h>

#define HIDDEN 4096
#define QKV_N 6144      // (32 + 2*8) * 128
#define T_LEN 2048
#define HD 128
#define N_HEADS 32
#define N_KV 8
#define SCALE 0.08838834764831845f  // 128^-0.5

// ---------------------------------------------------------------------------
// fp32 SGEMM: C[M][N] = A[M][K] @ B[K][N]; M,N multiples of 128, K of 8.
// 128x128 block tile, BK=8, 256 threads, 8x8 per thread (2x2 blocks of 4x4).
// ---------------------------------------------------------------------------
__global__ __launch_bounds__(256) void sgemm_kernel(
    const float* __restrict__ A, const float* __restrict__ B,
    float* __restrict__ C, int M, int N, int K) {
  __shared__ float As[8][128];  // transposed A tile: As[k][m]
  __shared__ float Bs[8][128];
  const int tid = threadIdx.x;
  const int tx = tid & 15;   // 0..15 -> N microtile
  const int ty = tid >> 4;   // 0..15 -> M microtile
  const int bm = blockIdx.y * 128;
  const int bn = blockIdx.x * 128;
  const int arow = tid >> 1;         // 0..127
  const int acol = (tid & 1) * 4;    // 0 or 4
  const int brow = tid >> 5;         // 0..7
  const int bcol = (tid & 31) * 4;   // 0..124

  const float* Aptr = A + (size_t)(bm + arow) * K + acol;
  const float* Bptr = B + (size_t)brow * N + bn + bcol;

  float acc[2][2][4][4];
#pragma unroll
  for (int a = 0; a < 2; ++a)
#pragma unroll
    for (int b = 0; b < 2; ++b)
#pragma unroll
      for (int i = 0; i < 4; ++i)
#pragma unroll
        for (int j = 0; j < 4; ++j) acc[a][b][i][j] = 0.f;

  float4 av = *(const float4*)(Aptr);
  float4 bv = *(const float4*)(Bptr);

  for (int k0 = 0; k0 < K; k0 += 8) {
    __syncthreads();
    As[acol + 0][arow] = av.x;
    As[acol + 1][arow] = av.y;
    As[acol + 2][arow] = av.z;
    As[acol + 3][arow] = av.w;
    *(float4*)&Bs[brow][bcol] = bv;
    __syncthreads();
    if (k0 + 8 < K) {
      av = *(const float4*)(Aptr + k0 + 8);
      bv = *(const float4*)(Bptr + (size_t)(k0 + 8) * N);
    }
#pragma unroll
    for (int k = 0; k < 8; ++k) {
      float4 a0 = *(const float4*)&As[k][ty * 4];
      float4 a1 = *(const float4*)&As[k][64 + ty * 4];
      float4 b0 = *(const float4*)&Bs[k][tx * 4];
      float4 b1 = *(const float4*)&Bs[k][64 + tx * 4];
      float ar[2][4] = {{a0.x, a0.y, a0.z, a0.w}, {a1.x, a1.y, a1.z, a1.w}};
      float br[2][4] = {{b0.x, b0.y, b0.z, b0.w}, {b1.x, b1.y, b1.z, b1.w}};
#pragma unroll
      for (int a = 0; a < 2; ++a)
#pragma unroll
        for (int b = 0; b < 2; ++b)
#pragma unroll
          for (int i = 0; i < 4; ++i)
#pragma unroll
            for (int j = 0; j < 4; ++j)
              acc[a][b][i][j] += ar[a][i] * br[b][j];
    }
  }

#pragma unroll
  for (int a = 0; a < 2; ++a)
#pragma unroll
    for (int i = 0; i < 4; ++i) {
      const int row = bm + a * 64 + ty * 4 + i;
      float* crow = C + (size_t)row * N + bn;
#pragma unroll
      for (int b = 0; b < 2; ++b) {
        float4 v = make_float4(acc[a][b][i][0], acc[a][b][i][1],
                               acc[a][b][i][2], acc[a][b][i][3]);
        *(float4*)&crow[b * 64 + tx * 4] = v;
      }
    }
}

// ---------------------------------------------------------------------------
// Fused per-head RMSNorm + partial RoPE, in-place on the qkv buffer.
// grid = (T, 40): heads 0..31 = Q (q_norm+rope), 32..39 = K (k_norm+rope).
// V heads untouched (in-place => pass-through). block = 128 (one per dim).
// ---------------------------------------------------------------------------
__global__ __launch_bounds__(128) void normrope_kernel(
    float* __restrict__ qkv, const int* __restrict__ positions,
    const float* __restrict__ qw, const float* __restrict__ kw) {
  const int t = blockIdx.x;
  const int hh = blockIdx.y;  // 0..39
  const int d = threadIdx.x;  // 0..127
  const bool isq = hh < N_HEADS;
  const int col = isq ? hh * HD : HIDDEN + (hh - N_HEADS) * HD;
  float* row = qkv + (size_t)t * QKV_N + col;
  const float* w = isq ? qw : kw;

  float x = row[d];
  float ss = x * x;
#pragma unroll
  for (int off = 32; off >= 1; off >>= 1) ss += __shfl_xor(ss, off);
  __shared__ float wsum[2];
  __shared__ float xs[128];
  if ((d & 63) == 0) wsum[d >> 6] = ss;
  __syncthreads();
  const float tot = wsum[0] + wsum[1];
  const float inv = rsqrtf(tot * (1.f / 128.f) + 1e-6f);
  const float xn = x * inv * w[d];
  xs[d] = xn;
  __syncthreads();

  float outv;
  if (d < 64) {
    const int idx = d & 31;
    const float invf = powf(1.0e6f, -(float)idx * (1.0f / 32.0f));
    const float fr = (float)positions[t] * invf;
    const float c = cosf(fr), s = sinf(fr);
    const float x1 = xs[idx], x2 = xs[idx + 32];
    outv = (d < 32) ? (x1 * c - x2 * s) : (x2 * c + x1 * s);
  } else {
    outv = xn;
  }
  row[d] = outv;
}

// ---------------------------------------------------------------------------
// Causal GQA flash attention, fp32. grid = (T/32, 32 heads), block = 256.
// Tiles: Q 32x128, K/V 32x128 (padded stride 132), online softmax.
// Out layout: [t][h*128+d] (row length 4096), ready for the O GEMM.
// ---------------------------------------------------------------------------
__global__ __launch_bounds__(256) void attn_kernel(
    const float* __restrict__ qkv, float* __restrict__ out) {
  const int qb = blockIdx.x;       // 0..63
  const int h = blockIdx.y;        // 0..31
  const int kvh = h >> 2;          // GQA group
  const int tid = threadIdx.x;

  __shared__ float Qs[32][132];
  __shared__ float Ks[32][132];
  __shared__ float Vs[32][132];
  __shared__ float Ps[32][33];
  __shared__ float mrow[32], lrow[32], frow[32];

  const int lrw = tid >> 3;            // 0..31 (load row / PV row)
  const int cbase = (tid & 7) * 16;    // 0..112 (load col base)
  const int t0 = qb * 32;

  // load Q tile (already normed+roped in qkv)
  {
    const float* src = qkv + (size_t)(t0 + lrw) * QKV_N + h * HD + cbase;
#pragma unroll
    for (int u = 0; u < 4; ++u)
      *(float4*)&Qs[lrw][cbase + 4 * u] = *(const float4*)(src + 4 * u);
  }
  if (tid < 32) {
    mrow[tid] = -1e30f;
    lrow[tid] = 0.f;
  }

  float o[4][4];
#pragma unroll
  for (int u = 0; u < 4; ++u)
#pragma unroll
    for (int j = 0; j < 4; ++j) o[u][j] = 0.f;

  // S-phase mapping: 2x2 per thread
  const int ty = tid >> 4, txx = tid & 15;
  const int r0 = ty * 2, c0 = txx * 2;
  // PV mapping: row lrw, d-cols (tid&7)*4 + 32*u
  const int dbase = (tid & 7) * 4;

  float4 kreg[4], vreg[4];
  {
    const float* ksrc = qkv + (size_t)(0 + lrw) * QKV_N + HIDDEN + kvh * HD + cbase;
#pragma unroll
    for (int u = 0; u < 4; ++u) {
      kreg[u] = *(const float4*)(ksrc + 4 * u);
      vreg[u] = *(const float4*)(ksrc + 1024 + 4 * u);  // v is 1024 floats after k
    }
  }

  for (int j = 0; j <= qb; ++j) {
    __syncthreads();  // previous PV / P reads done
#pragma unroll
    for (int u = 0; u < 4; ++u) {
      *(float4*)&Ks[lrw][cbase + 4 * u] = kreg[u];
      *(float4*)&Vs[lrw][cbase + 4 * u] = vreg[u];
    }
    __syncthreads();
    if (j < qb) {
      const float* ksrc =
          qkv + (size_t)((j + 1) * 32 + lrw) * QKV_N + HIDDEN + kvh * HD + cbase;
#pragma unroll
      for (int u = 0; u < 4; ++u) {
        kreg[u] = *(const float4*)(ksrc + 4 * u);
        vreg[u] = *(const float4*)(ksrc + 1024 + 4 * u);
      }
    }

    // ---- S = Q K^T (2x2 per thread) ----
    float s00 = 0.f, s01 = 0.f, s10 = 0.f, s11 = 0.f;
#pragma unroll 8
    for (int k = 0; k < 128; k += 4) {
      float4 qa = *(const float4*)&Qs[r0][k];
      float4 qc = *(const float4*)&Qs[r0 + 1][k];
      float4 ka = *(const float4*)&Ks[c0][k];
      float4 kc = *(const float4*)&Ks[c0 + 1][k];
      s00 += qa.x * ka.x + qa.y * ka.y + qa.z * ka.z + qa.w * ka.w;
      s01 += qa.x * kc.x + qa.y * kc.y + qa.z * kc.z + qa.w * kc.w;
      s10 += qc.x * ka.x + qc.y * ka.y + qc.z * ka.z + qc.w * ka.w;
      s11 += qc.x * kc.x + qc.y * kc.y + qc.z * kc.z + qc.w * kc.w;
    }
    {
      const int sbase = j * 32;
      float sv;
      sv = s00 * SCALE; if (sbase + c0 > t0 + r0) sv = -1e30f; Ps[r0][c0] = sv;
      sv = s01 * SCALE; if (sbase + c0 + 1 > t0 + r0) sv = -1e30f; Ps[r0][c0 + 1] = sv;
      sv = s10 * SCALE; if (sbase + c0 > t0 + r0 + 1) sv = -1e30f; Ps[r0 + 1][c0] = sv;
      sv = s11 * SCALE; if (sbase + c0 + 1 > t0 + r0 + 1) sv = -1e30f; Ps[r0 + 1][c0 + 1] = sv;
    }
    __syncthreads();

    // ---- online softmax over rows (4 threads per row) ----
    if (tid < 128) {
      const int r = tid >> 2, q4 = tid & 3;
      float pm = -1e30f;
#pragma unroll
      for (int c = q4 * 8; c < q4 * 8 + 8; ++c) pm = fmaxf(pm, Ps[r][c]);
      pm = fmaxf(pm, __shfl_xor(pm, 1));
      pm = fmaxf(pm, __shfl_xor(pm, 2));
      const float mold = mrow[r];
      const float mnew = fmaxf(mold, pm);
      float psum = 0.f;
#pragma unroll
      for (int c = q4 * 8; c < q4 * 8 + 8; ++c) {
        const float p = __expf(Ps[r][c] - mnew);
        Ps[r][c] = p;
        psum += p;
      }
      psum += __shfl_xor(psum, 1);
      psum += __shfl_xor(psum, 2);
      if (q4 == 0) {
        const float f = __expf(mold - mnew);
        frow[r] = f;
        mrow[r] = mnew;
        lrow[r] = lrow[r] * f + psum;
      }
    }
    __syncthreads();

    // ---- rescale + PV ----
    const float f = frow[lrw];
#pragma unroll
    for (int u = 0; u < 4; ++u)
#pragma unroll
      for (int jj = 0; jj < 4; ++jj) o[u][jj] *= f;
#pragma unroll 4
    for (int c = 0; c < 32; ++c) {
      const float p = Ps[lrw][c];
#pragma unroll
      for (int u = 0; u < 4; ++u) {
        float4 v = *(const float4*)&Vs[c][dbase + 32 * u];
        o[u][0] += p * v.x;
        o[u][1] += p * v.y;
        o[u][2] += p * v.z;
        o[u][3] += p * v.w;
      }
    }
  }

  const float linv = 1.0f / lrow[lrw];
  float* dst = out + (size_t)(t0 + lrw) * HIDDEN + h * HD + dbase;
#pragma unroll
  for (int u = 0; u < 4; ++u) {
    float4 v = make_float4(o[u][0] * linv, o[u][1] * linv, o[u][2] * linv,
                           o[u][3] * linv);
    *(float4*)&dst[32 * u] = v;
  }
}

// ---------------------------------------------------------------------------
extern "C" void kernel_launch(void* const* d_in, const int* in_sizes, int n_in,
                              void* d_out, int out_size, void* d_ws,
                              size_t ws_size, hipStream_t stream) {
  const float* hidden = (const float*)d_in[0];
  const int* positions = (const int*)d_in[1];
  const float* w_qkv = (const float*)d_in[2];
  const float* w_o = (const float*)d_in[3];
  const float* q_norm_w = (const float*)d_in[4];
  const float* k_norm_w = (const float*)d_in[5];
  float* out = (float*)d_out;

  float* qkv = (float*)d_ws;                       // 2048*6144 f32 = 50.3 MB
  float* attn = qkv + (size_t)T_LEN * QKV_N;       // 2048*4096 f32 = 33.6 MB

  // 1) qkv = hidden @ w_qkv
  sgemm_kernel<<<dim3(QKV_N / 128, T_LEN / 128), 256, 0, stream>>>(
      hidden, w_qkv, qkv, T_LEN, QKV_N, HIDDEN);
  // 2) in-place RMSNorm + RoPE on q and k heads
  normrope_kernel<<<dim3(T_LEN, N_HEADS + N_KV), 128, 0, stream>>>(
      qkv, positions, q_norm_w, k_norm_w);
  // 3) causal GQA flash attention -> attn buffer [t][h*128+d]
  attn_kernel<<<dim3(T_LEN / 32, N_HEADS), 256, 0, stream>>>(qkv, attn);
  // 4) out = attn @ w_o
  sgemm_kernel<<<dim3(HIDDEN / 128, T_LEN / 128), 256, 0, stream>>>(
      attn, w_o, out, T_LEN, HIDDEN, HIDDEN);
}

// Round 5
// 1462.065 us; speedup vs baseline: 2.6013x; 2.6013x over previous
//
#include <hip/hip_runtime.h>
#include <math.h>

#define HIDDEN 4096
#define QKV_N 6144      // (32 + 2*8) * 128
#define T_LEN 2048
#define HD 128
#define N_HEADS 32
#define N_KV 8
#define SCALE 0.08838834764831845f  // 128^-0.5

typedef unsigned short u16;
typedef __attribute__((ext_vector_type(8))) short bf16x8;
typedef __attribute__((ext_vector_type(4))) float f32x4;

// fp32 -> bf16 with round-to-nearest-even
__device__ __forceinline__ u16 f2b(float x) {
  unsigned int u = __builtin_bit_cast(unsigned int, x);
  u += 0x7fffu + ((u >> 16) & 1u);
  return (u16)(u >> 16);
}

typedef const __attribute__((address_space(1))) void* gas_ptr;
typedef __attribute__((address_space(3))) void* las_ptr;
__device__ __forceinline__ void gll16(const void* g, void* l) {
  __builtin_amdgcn_global_load_lds((gas_ptr)g, (las_ptr)l, 16, 0, 0);
}

// ---------------------------------------------------------------------------
// elementwise fp32 -> bf16 cast (4 elems/thread)
// ---------------------------------------------------------------------------
__global__ __launch_bounds__(256) void cast_bf16_kernel(
    const float* __restrict__ in, u16* __restrict__ out) {
  const size_t i = ((size_t)blockIdx.x * 256 + threadIdx.x) * 4;
  f32x4 v = *(const f32x4*)(in + i);
  ushort4 o;
  o.x = f2b(v[0]); o.y = f2b(v[1]); o.z = f2b(v[2]); o.w = f2b(v[3]);
  *(ushort4*)(out + i) = o;
}

// ---------------------------------------------------------------------------
// W [K][N] fp32 -> WT [N][K] bf16 (32x32 LDS tile transpose)
// grid = (N/32, K/32), 256 threads
// ---------------------------------------------------------------------------
__global__ __launch_bounds__(256) void transpose_cast_kernel(
    const float* __restrict__ W, u16* __restrict__ WT, int K, int N) {
  __shared__ float t[32][33];
  const int n0 = blockIdx.x * 32, k0 = blockIdx.y * 32;
  const int c = threadIdx.x & 31;
  const int r0 = threadIdx.x >> 5;  // 0..7
#pragma unroll
  for (int j = 0; j < 4; ++j) {
    const int r = r0 + 8 * j;
    t[c][r] = W[(size_t)(k0 + r) * N + n0 + c];
  }
  __syncthreads();
#pragma unroll
  for (int j = 0; j < 4; ++j) {
    const int n = r0 + 8 * j;
    WT[(size_t)(n0 + n) * K + k0 + c] = f2b(t[n][c]);
  }
}

// ---------------------------------------------------------------------------
// bf16 MFMA GEMM: C_f32[M][N] = A_bf16[M][K] @ BT_bf16[N][K]^T
// 128x128 tile, BK=32, 256 threads (4 waves, 2x2), 16x16x32 MFMA, 4x4 frags.
// Staging via global_load_lds width 16 into linear [128][32] bf16 LDS tiles.
// ---------------------------------------------------------------------------
__global__ __launch_bounds__(256) void gemm_bf16_kernel(
    const u16* __restrict__ A, const u16* __restrict__ BT,
    float* __restrict__ C, int M, int N, int K) {
  __shared__ __align__(16) u16 As[128 * 32];
  __shared__ __align__(16) u16 Bs[128 * 32];
  const int tid = threadIdx.x;
  const int w = tid >> 6, l = tid & 63;
  const int bm = blockIdx.y * 128, bn = blockIdx.x * 128;

  // staging addresses: row = i*64 + w*16 + (l>>2), col granule = l&3 (8 elems)
  // LDS byte offset = w*1024 + l*16  (wave-uniform base + lane*16: gll-legal)
  const int rl = w * 16 + (l >> 2);
  const int kc = (l & 3) * 8;
  const u16* gA0 = A + (size_t)(bm + rl) * K + kc;
  const u16* gA1 = A + (size_t)(bm + rl + 64) * K + kc;
  const u16* gB0 = BT + (size_t)(bn + rl) * K + kc;
  const u16* gB1 = BT + (size_t)(bn + rl + 64) * K + kc;
  u16* lA0 = As + rl * 32 + kc;
  u16* lA1 = As + (rl + 64) * 32 + kc;
  u16* lB0 = Bs + rl * 32 + kc;
  u16* lB1 = Bs + (rl + 64) * 32 + kc;

  // fragment read bases: row = wr*64 + mi*16 + (l&15), k-granule = l>>4
  const int wr = w >> 1, wc = w & 1;
  const u16* pa = As + (size_t)(wr * 64 + (l & 15)) * 32 + (l >> 4) * 8;
  const u16* pb = Bs + (size_t)(wc * 64 + (l & 15)) * 32 + (l >> 4) * 8;

  f32x4 acc[4][4];
#pragma unroll
  for (int i = 0; i < 4; ++i)
#pragma unroll
    for (int j = 0; j < 4; ++j) acc[i][j] = (f32x4){0.f, 0.f, 0.f, 0.f};

  gll16(gA0, lA0); gll16(gA1, lA1);
  gll16(gB0, lB0); gll16(gB1, lB1);

  const int NK = K >> 5;
  for (int kt = 0; kt < NK; ++kt) {
    __syncthreads();  // drains vmcnt: staged tile visible
    bf16x8 af[4], bg[4];
#pragma unroll
    for (int i = 0; i < 4; ++i) {
      af[i] = *(const bf16x8*)(pa + i * 512);
      bg[i] = *(const bf16x8*)(pb + i * 512);
    }
#pragma unroll
    for (int mi = 0; mi < 4; ++mi)
#pragma unroll
      for (int ni = 0; ni < 4; ++ni)
        acc[mi][ni] = __builtin_amdgcn_mfma_f32_16x16x32_bf16(
            af[mi], bg[ni], acc[mi][ni], 0, 0, 0);
    __syncthreads();  // all LDS reads done before restage
    if (kt + 1 < NK) {
      const int ko = (kt + 1) * 32;
      gll16(gA0 + ko, lA0); gll16(gA1 + ko, lA1);
      gll16(gB0 + ko, lB0); gll16(gB1 + ko, lB1);
    }
  }

  // C/D layout (m89/m91 verified): row = (l>>4)*4 + reg, col = l&15
#pragma unroll
  for (int mi = 0; mi < 4; ++mi) {
    const int row = bm + wr * 64 + mi * 16 + (l >> 4) * 4;
#pragma unroll
    for (int ni = 0; ni < 4; ++ni) {
      const int col = bn + wc * 64 + ni * 16 + (l & 15);
      float* cp = C + (size_t)row * N + col;
#pragma unroll
      for (int r = 0; r < 4; ++r) cp[(size_t)r * N] = acc[mi][ni][r];
    }
  }
}

// ---------------------------------------------------------------------------
// Fused per-head RMSNorm + partial RoPE, in-place on the fp32 qkv buffer.
// ---------------------------------------------------------------------------
__global__ __launch_bounds__(128) void normrope_kernel(
    float* __restrict__ qkv, const int* __restrict__ positions,
    const float* __restrict__ qw, const float* __restrict__ kw) {
  const int t = blockIdx.x;
  const int hh = blockIdx.y;  // 0..39
  const int d = threadIdx.x;  // 0..127
  const bool isq = hh < N_HEADS;
  const int col = isq ? hh * HD : HIDDEN + (hh - N_HEADS) * HD;
  float* row = qkv + (size_t)t * QKV_N + col;
  const float* w = isq ? qw : kw;

  float x = row[d];
  float ss = x * x;
#pragma unroll
  for (int off = 32; off >= 1; off >>= 1) ss += __shfl_xor(ss, off);
  __shared__ float wsum[2];
  __shared__ float xs[128];
  if ((d & 63) == 0) wsum[d >> 6] = ss;
  __syncthreads();
  const float tot = wsum[0] + wsum[1];
  const float inv = rsqrtf(tot * (1.f / 128.f) + 1e-6f);
  const float xn = x * inv * w[d];
  xs[d] = xn;
  __syncthreads();

  float outv;
  if (d < 64) {
    const int idx = d & 31;
    const float invf = powf(1.0e6f, -(float)idx * (1.0f / 32.0f));
    const float fr = (float)positions[t] * invf;
    const float c = cosf(fr), s = sinf(fr);
    const float x1 = xs[idx], x2 = xs[idx + 32];
    outv = (d < 32) ? (x1 * c - x2 * s) : (x2 * c + x1 * s);
  } else {
    outv = xn;
  }
  row[d] = outv;
}

// ---------------------------------------------------------------------------
// Causal GQA flash attention, fp32 compute, bf16 output.
// grid = (T/64, 32 heads), 256 threads (4 waves). Q tile 64x128, K/V 32x128.
// S in registers (2 rows x 4 strided cols / lane); 8-lane shfl softmax.
// LDS tiles XOR-swizzled on 16B granules (granule ^ (row&7)): conflict-free.
// ---------------------------------------------------------------------------
__global__ __launch_bounds__(256) void attn2_kernel(
    const float* __restrict__ qkv, u16* __restrict__ outB) {
  __shared__ __align__(16) float Qs[64 * 128];
  __shared__ __align__(16) float Ks[32 * 128];
  __shared__ __align__(16) float Vs[32 * 128];

  const int qb = gridDim.x - 1 - blockIdx.x;  // big blocks first
  const int h = blockIdx.y;
  const int kvh = h >> 2;
  const int tid = threadIdx.x;
  const int w = tid >> 6, l = tid & 63;
  const int g = l >> 3, e = l & 7;
  const int r0 = w * 16 + g * 2;  // local Q rows r0, r0+1
  const int t0 = qb * 64;

  // ---- load + scale Q tile (swizzled) ----
  {
    const int row = tid >> 2;          // 0..63
    const int gb = (tid & 3) * 8;      // granule base (granule = 4 floats)
    const float* src = qkv + (size_t)(t0 + row) * QKV_N + h * HD + gb * 4;
    float* dst = Qs + row * 128;
    const int rs = row & 7;
#pragma unroll
    for (int j = 0; j < 8; ++j) {
      f32x4 v = *(const f32x4*)(src + 4 * j);
      v *= SCALE;
      *(f32x4*)(dst + ((gb + j) ^ rs) * 4) = v;
    }
  }

  // ---- K/V register prefetch (tile 0) ----
  // thread covers granules kgb..kgb+3 of row krow (float off = kgb*4 + 4u)
  const int krow = tid >> 3, kgb = (tid & 7) * 4;  // granule base
  f32x4 kreg[4], vreg[4];
  {
    const float* s2 = qkv + (size_t)krow * QKV_N + HIDDEN + kvh * HD + kgb * 4;
#pragma unroll
    for (int u = 0; u < 4; ++u) {
      kreg[u] = *(const f32x4*)(s2 + 4 * u);
      vreg[u] = *(const f32x4*)(s2 + 1024 + 4 * u);
    }
  }

  float m0 = -1e30f, m1 = -1e30f, l0 = 0.f, l1 = 0.f;
  f32x4 o0[4], o1[4];
#pragma unroll
  for (int u = 0; u < 4; ++u) {
    o0[u] = (f32x4){0.f, 0.f, 0.f, 0.f};
    o1[u] = (f32x4){0.f, 0.f, 0.f, 0.f};
  }

  const int rs0 = r0 & 7, rs1 = (r0 + 1) & 7;
  const float* q0p = Qs + r0 * 128;
  const float* q1p = Qs + (r0 + 1) * 128;
  const float* Kp0 = Ks + (e) * 128;
  const float* Kp1 = Ks + (e + 8) * 128;
  const float* Kp2 = Ks + (e + 16) * 128;
  const float* Kp3 = Ks + (e + 24) * 128;

  const int NT = 2 * (qb + 1);
  for (int jt = 0; jt < NT; ++jt) {
    __syncthreads();  // prev tile reads done (also covers Q writes, iter 0)
    {
      float* kd = Ks + krow * 128;
      float* vd = Vs + krow * 128;
      const int rs = krow & 7;
#pragma unroll
      for (int u = 0; u < 4; ++u) {
        const int gph = ((kgb + u) ^ rs) * 4;
        *(f32x4*)(kd + gph) = kreg[u];
        *(f32x4*)(vd + gph) = vreg[u];
      }
    }
    __syncthreads();
    if (jt + 1 < NT) {
      const float* s2 =
          qkv + (size_t)((jt + 1) * 32 + krow) * QKV_N + HIDDEN + kvh * HD + kgb * 4;
#pragma unroll
      for (int u = 0; u < 4; ++u) {
        kreg[u] = *(const f32x4*)(s2 + 4 * u);
        vreg[u] = *(const f32x4*)(s2 + 1024 + 4 * u);
      }
    }

    // ---- S = (Q*scale) K^T : s0/s1[u] for cols e+8u ----
    float s0[4] = {0.f, 0.f, 0.f, 0.f}, s1[4] = {0.f, 0.f, 0.f, 0.f};
#pragma unroll
    for (int k4 = 0; k4 < 32; ++k4) {
      const f32x4 qa = *(const f32x4*)(q0p + ((k4 ^ rs0) << 2));
      const f32x4 qc = *(const f32x4*)(q1p + ((k4 ^ rs1) << 2));
      const int kx = (k4 ^ e) << 2;
      const f32x4 k0v = *(const f32x4*)(Kp0 + kx);
      const f32x4 k1v = *(const f32x4*)(Kp1 + kx);
      const f32x4 k2v = *(const f32x4*)(Kp2 + kx);
      const f32x4 k3v = *(const f32x4*)(Kp3 + kx);
#pragma unroll
      for (int i = 0; i < 4; ++i) {
        s0[0] += qa[i] * k0v[i]; s0[1] += qa[i] * k1v[i];
        s0[2] += qa[i] * k2v[i]; s0[3] += qa[i] * k3v[i];
        s1[0] += qc[i] * k0v[i]; s1[1] += qc[i] * k1v[i];
        s1[2] += qc[i] * k2v[i]; s1[3] += qc[i] * k3v[i];
      }
    }

    // ---- causal mask (only last two tiles can clip) ----
    if (jt >= NT - 2) {
      const int colb = jt * 32 + e;
      const int rg0 = t0 + r0;
#pragma unroll
      for (int u = 0; u < 4; ++u) {
        if (colb + 8 * u > rg0) s0[u] = -1e30f;
        if (colb + 8 * u > rg0 + 1) s1[u] = -1e30f;
      }
    }

    // ---- online softmax (row = 8-lane group) ----
    float pm0 = fmaxf(fmaxf(s0[0], s0[1]), fmaxf(s0[2], s0[3]));
    float pm1 = fmaxf(fmaxf(s1[0], s1[1]), fmaxf(s1[2], s1[3]));
    pm0 = fmaxf(pm0, __shfl_xor(pm0, 1));
    pm0 = fmaxf(pm0, __shfl_xor(pm0, 2));
    pm0 = fmaxf(pm0, __shfl_xor(pm0, 4));
    pm1 = fmaxf(pm1, __shfl_xor(pm1, 1));
    pm1 = fmaxf(pm1, __shfl_xor(pm1, 2));
    pm1 = fmaxf(pm1, __shfl_xor(pm1, 4));
    const float mn0 = fmaxf(m0, pm0), mn1 = fmaxf(m1, pm1);
    const float sc0 = __expf(m0 - mn0), sc1 = __expf(m1 - mn1);
    m0 = mn0; m1 = mn1;
    float ps0 = 0.f, ps1 = 0.f;
#pragma unroll
    for (int u = 0; u < 4; ++u) {
      s0[u] = __expf(s0[u] - mn0); ps0 += s0[u];
      s1[u] = __expf(s1[u] - mn1); ps1 += s1[u];
    }
    ps0 += __shfl_xor(ps0, 1); ps0 += __shfl_xor(ps0, 2); ps0 += __shfl_xor(ps0, 4);
    ps1 += __shfl_xor(ps1, 1); ps1 += __shfl_xor(ps1, 2); ps1 += __shfl_xor(ps1, 4);
    l0 = l0 * sc0 + ps0;
    l1 = l1 * sc1 + ps1;
#pragma unroll
    for (int u = 0; u < 4; ++u) { o0[u] *= sc0; o1[u] *= sc1; }

    // ---- PV: O[r][e*4+32u+j] += sum_c P[r][c] * V[c][...] ----
#pragma unroll
    for (int c = 0; c < 32; ++c) {
      const float p0 = __shfl(s0[c >> 3], c & 7, 8);
      const float p1 = __shfl(s1[c >> 3], c & 7, 8);
      const float* vrow = Vs + c * 128;
      const int rsv = c & 7;
#pragma unroll
      for (int u = 0; u < 4; ++u) {
        const f32x4 v = *(const f32x4*)(vrow + (((e + 8 * u) ^ rsv) << 2));
        o0[u] += p0 * v;
        o1[u] += p1 * v;
      }
    }
  }

  const float li0 = 1.f / l0, li1 = 1.f / l1;
  u16* d0 = outB + (size_t)(t0 + r0) * HIDDEN + h * HD + e * 4;
  u16* d1 = d0 + HIDDEN;
#pragma unroll
  for (int u = 0; u < 4; ++u) {
    ushort4 pk0, pk1;
    pk0.x = f2b(o0[u][0] * li0); pk0.y = f2b(o0[u][1] * li0);
    pk0.z = f2b(o0[u][2] * li0); pk0.w = f2b(o0[u][3] * li0);
    pk1.x = f2b(o1[u][0] * li1); pk1.y = f2b(o1[u][1] * li1);
    pk1.z = f2b(o1[u][2] * li1); pk1.w = f2b(o1[u][3] * li1);
    *(ushort4*)(d0 + 32 * u) = pk0;
    *(ushort4*)(d1 + 32 * u) = pk1;
  }
}

// ---------------------------------------------------------------------------
extern "C" void kernel_launch(void* const* d_in, const int* in_sizes, int n_in,
                              void* d_out, int out_size, void* d_ws,
                              size_t ws_size, hipStream_t stream) {
  const float* hidden = (const float*)d_in[0];
  const int* positions = (const int*)d_in[1];
  const float* w_qkv = (const float*)d_in[2];
  const float* w_o = (const float*)d_in[3];
  const float* q_norm_w = (const float*)d_in[4];
  const float* k_norm_w = (const float*)d_in[5];
  float* out = (float*)d_out;

  // workspace layout
  u16* hiddenB = (u16*)d_ws;                                   // 16.8 MB
  u16* wqkvT = hiddenB + (size_t)T_LEN * HIDDEN;               // 50.3 MB
  u16* woT = wqkvT + (size_t)QKV_N * HIDDEN;                   // 33.6 MB
  float* qkv = (float*)(woT + (size_t)HIDDEN * HIDDEN);        // 50.3 MB
  u16* attnB = (u16*)(qkv + (size_t)T_LEN * QKV_N);            // 16.8 MB

  // prep: casts + weight transposes
  cast_bf16_kernel<<<(T_LEN * HIDDEN) / 1024, 256, 0, stream>>>(hidden, hiddenB);
  transpose_cast_kernel<<<dim3(QKV_N / 32, HIDDEN / 32), 256, 0, stream>>>(
      w_qkv, wqkvT, HIDDEN, QKV_N);
  transpose_cast_kernel<<<dim3(HIDDEN / 32, HIDDEN / 32), 256, 0, stream>>>(
      w_o, woT, HIDDEN, HIDDEN);

  // 1) qkv = hidden @ w_qkv  (bf16 MFMA, fp32 out)
  gemm_bf16_kernel<<<dim3(QKV_N / 128, T_LEN / 128), 256, 0, stream>>>(
      hiddenB, wqkvT, qkv, T_LEN, QKV_N, HIDDEN);
  // 2) RMSNorm + RoPE in-place (fp32)
  normrope_kernel<<<dim3(T_LEN, N_HEADS + N_KV), 128, 0, stream>>>(
      qkv, positions, q_norm_w, k_norm_w);
  // 3) causal GQA flash attention (fp32 compute) -> bf16 [t][h*128+d]
  attn2_kernel<<<dim3(T_LEN / 64, N_HEADS), 256, 0, stream>>>(qkv, attnB);
  // 4) out = attn @ w_o  (bf16 MFMA, fp32 out)
  gemm_bf16_kernel<<<dim3(HIDDEN / 128, T_LEN / 128), 256, 0, stream>>>(
      attnB, woT, out, T_LEN, HIDDEN, HIDDEN);
}

// Round 6
// 485.193 us; speedup vs baseline: 7.8385x; 3.0134x over previous
//
#include <hip/hip_runtime.h>
#include <math.h>

#define HIDDEN 4096
#define QKV_N 6144      // (32 + 2*8) * 128
#define T_LEN 2048
#define HD 128
#define N_HEADS 32
#define N_KV 8
#define SCALE 0.08838834764831845f  // 128^-0.5

typedef unsigned short u16;
typedef unsigned int u32;
typedef __attribute__((ext_vector_type(8))) short bf16x8;
typedef __attribute__((ext_vector_type(4))) float f32x4;

// fp32 -> bf16 round-to-nearest-even
__device__ __forceinline__ u16 f2b(float x) {
  u32 u = __builtin_bit_cast(u32, x);
  u += 0x7fffu + ((u >> 16) & 1u);
  return (u16)(u >> 16);
}

typedef const __attribute__((address_space(1))) void* gas_ptr;
typedef __attribute__((address_space(3))) void* las_ptr;
__device__ __forceinline__ void gll16(const void* g, void* l) {
  __builtin_amdgcn_global_load_lds((gas_ptr)g, (las_ptr)l, 16, 0, 0);
}

// ---------------------------------------------------------------------------
// elementwise fp32 -> bf16 cast (4 elems/thread)
// ---------------------------------------------------------------------------
__global__ __launch_bounds__(256) void cast_bf16_kernel(
    const float* __restrict__ in, u16* __restrict__ out) {
  const size_t i = ((size_t)blockIdx.x * 256 + threadIdx.x) * 4;
  f32x4 v = *(const f32x4*)(in + i);
  ushort4 o;
  o.x = f2b(v[0]); o.y = f2b(v[1]); o.z = f2b(v[2]); o.w = f2b(v[3]);
  *(ushort4*)(out + i) = o;
}

// ---------------------------------------------------------------------------
// W [K][N] fp32 -> WT [N][K] bf16 (32x32 LDS tile transpose)
// ---------------------------------------------------------------------------
__global__ __launch_bounds__(256) void transpose_cast_kernel(
    const float* __restrict__ W, u16* __restrict__ WT, int K, int N) {
  __shared__ float t[32][33];
  const int n0 = blockIdx.x * 32, k0 = blockIdx.y * 32;
  const int c = threadIdx.x & 31;
  const int r0 = threadIdx.x >> 5;
#pragma unroll
  for (int j = 0; j < 4; ++j) {
    const int r = r0 + 8 * j;
    t[c][r] = W[(size_t)(k0 + r) * N + n0 + c];
  }
  __syncthreads();
#pragma unroll
  for (int j = 0; j < 4; ++j) {
    const int n = r0 + 8 * j;
    WT[(size_t)(n0 + n) * K + k0 + c] = f2b(t[n][c]);
  }
}

// ---------------------------------------------------------------------------
// bf16 MFMA GEMM: C_f32[M][N] = A_bf16[M][K] @ BT_bf16[N][K]^T  (128x128, BK=32)
// ---------------------------------------------------------------------------
__global__ __launch_bounds__(256) void gemm_bf16_kernel(
    const u16* __restrict__ A, const u16* __restrict__ BT,
    float* __restrict__ C, int M, int N, int K) {
  __shared__ __align__(16) u16 As[128 * 32];
  __shared__ __align__(16) u16 Bs[128 * 32];
  const int tid = threadIdx.x;
  const int w = tid >> 6, l = tid & 63;
  const int bm = blockIdx.y * 128, bn = blockIdx.x * 128;

  const int rl = w * 16 + (l >> 2);
  const int kc = (l & 3) * 8;
  const u16* gA0 = A + (size_t)(bm + rl) * K + kc;
  const u16* gA1 = A + (size_t)(bm + rl + 64) * K + kc;
  const u16* gB0 = BT + (size_t)(bn + rl) * K + kc;
  const u16* gB1 = BT + (size_t)(bn + rl + 64) * K + kc;
  u16* lA0 = As + rl * 32 + kc;
  u16* lA1 = As + (rl + 64) * 32 + kc;
  u16* lB0 = Bs + rl * 32 + kc;
  u16* lB1 = Bs + (rl + 64) * 32 + kc;

  const int wr = w >> 1, wc = w & 1;
  const u16* pa = As + (size_t)(wr * 64 + (l & 15)) * 32 + (l >> 4) * 8;
  const u16* pb = Bs + (size_t)(wc * 64 + (l & 15)) * 32 + (l >> 4) * 8;

  f32x4 acc[4][4];
#pragma unroll
  for (int i = 0; i < 4; ++i)
#pragma unroll
    for (int j = 0; j < 4; ++j) acc[i][j] = (f32x4){0.f, 0.f, 0.f, 0.f};

  gll16(gA0, lA0); gll16(gA1, lA1);
  gll16(gB0, lB0); gll16(gB1, lB1);

  const int NK = K >> 5;
  for (int kt = 0; kt < NK; ++kt) {
    __syncthreads();
    bf16x8 af[4], bg[4];
#pragma unroll
    for (int i = 0; i < 4; ++i) {
      af[i] = *(const bf16x8*)(pa + i * 512);
      bg[i] = *(const bf16x8*)(pb + i * 512);
    }
#pragma unroll
    for (int mi = 0; mi < 4; ++mi)
#pragma unroll
      for (int ni = 0; ni < 4; ++ni)
        acc[mi][ni] = __builtin_amdgcn_mfma_f32_16x16x32_bf16(
            af[mi], bg[ni], acc[mi][ni], 0, 0, 0);
    __syncthreads();
    if (kt + 1 < NK) {
      const int ko = (kt + 1) * 32;
      gll16(gA0 + ko, lA0); gll16(gA1 + ko, lA1);
      gll16(gB0 + ko, lB0); gll16(gB1 + ko, lB1);
    }
  }

#pragma unroll
  for (int mi = 0; mi < 4; ++mi) {
    const int row = bm + wr * 64 + mi * 16 + (l >> 4) * 4;
#pragma unroll
    for (int ni = 0; ni < 4; ++ni) {
      const int col = bn + wc * 64 + ni * 16 + (l & 15);
      float* cp = C + (size_t)row * N + col;
#pragma unroll
      for (int r = 0; r < 4; ++r) cp[(size_t)r * N] = acc[mi][ni][r];
    }
  }
}

// ---------------------------------------------------------------------------
// Fused per-head RMSNorm + partial RoPE -> packed bf16.
// Q (scale folded): Qp[h][t][128]; K: Kp[kvh][t][128]. grid (T, 40), 128 thr.
// ---------------------------------------------------------------------------
__global__ __launch_bounds__(128) void normrope_pack_kernel(
    const float* __restrict__ qkv, const int* __restrict__ positions,
    const float* __restrict__ qw, const float* __restrict__ kw,
    u16* __restrict__ Qp, u16* __restrict__ Kp) {
  const int t = blockIdx.x;
  const int hh = blockIdx.y;  // 0..39
  const int d = threadIdx.x;  // 0..127
  const bool isq = hh < N_HEADS;
  const int col = isq ? hh * HD : HIDDEN + (hh - N_HEADS) * HD;
  const float* row = qkv + (size_t)t * QKV_N + col;
  const float* w = isq ? qw : kw;

  float x = row[d];
  float ss = x * x;
#pragma unroll
  for (int off = 32; off >= 1; off >>= 1) ss += __shfl_xor(ss, off);
  __shared__ float wsum[2];
  __shared__ float xs[128];
  if ((d & 63) == 0) wsum[d >> 6] = ss;
  __syncthreads();
  const float tot = wsum[0] + wsum[1];
  const float inv = rsqrtf(tot * (1.f / 128.f) + 1e-6f);
  const float xn = x * inv * w[d];
  xs[d] = xn;
  __syncthreads();

  float outv;
  if (d < 64) {
    const int idx = d & 31;
    const float invf = powf(1.0e6f, -(float)idx * (1.0f / 32.0f));
    const float fr = (float)positions[t] * invf;
    const float c = cosf(fr), s = sinf(fr);
    const float x1 = xs[idx], x2 = xs[idx + 32];
    outv = (d < 32) ? (x1 * c - x2 * s) : (x2 * c + x1 * s);
  } else {
    outv = xn;
  }
  if (isq) {
    Qp[((size_t)hh * T_LEN + t) * HD + d] = f2b(outv * SCALE);
  } else {
    Kp[((size_t)(hh - N_HEADS) * T_LEN + t) * HD + d] = f2b(outv);
  }
}

// ---------------------------------------------------------------------------
// V transpose+cast: qkv V region fp32 [t][d] -> Vtp[kvh][d][t] bf16.
// grid (T/32, 8), 256 threads, 32x128 LDS tile.
// ---------------------------------------------------------------------------
__global__ __launch_bounds__(256) void vtrans_kernel(
    const float* __restrict__ qkv, u16* __restrict__ Vtp) {
  __shared__ float tile[32][132];
  const int t0 = blockIdx.x * 32;
  const int kvh = blockIdx.y;
  const int tv = threadIdx.x >> 3;          // 0..31
  const int c0 = (threadIdx.x & 7) * 16;    // 0..112
  const float* src =
      qkv + (size_t)(t0 + tv) * QKV_N + (HIDDEN + 1024) + kvh * HD + c0;
#pragma unroll
  for (int u = 0; u < 4; ++u)
    *(f32x4*)&tile[tv][c0 + 4 * u] = *(const f32x4*)(src + 4 * u);
  __syncthreads();
  const int dd = threadIdx.x >> 1;   // 0..127
  const int half = threadIdx.x & 1;  // 0,1
  u16 buf[16];
#pragma unroll
  for (int p = 0; p < 16; ++p) buf[p] = f2b(tile[half * 16 + p][dd]);
  u16* dst = Vtp + ((size_t)kvh * HD + dd) * T_LEN + t0 + half * 16;
  *(uint4*)dst = *(uint4*)&buf[0];
  *(uint4*)(dst + 8) = *(uint4*)&buf[8];
}

// ---------------------------------------------------------------------------
// MFMA causal GQA flash attention. grid (32 qb, 32 h), 256 thr (4 waves).
// Swapped QK^T (S^T = K@Q^T) so softmax stats reduce with 2 shfl_xor.
// Q 64x128 staged once; K 32x128 / Vt 128x32 double-buffered via
// global_load_lds with pre-swizzled global source (rule #21).
// P relayout to A-fragments via per-wave 1KB LDS bounce (no barrier).
// ---------------------------------------------------------------------------
__global__ __launch_bounds__(256, 3) void attn3_kernel(
    const u16* __restrict__ Qp, const u16* __restrict__ Kp,
    const u16* __restrict__ Vtp, u16* __restrict__ outB) {
  __shared__ __align__(16) u16 Qs[64 * 128];
  __shared__ __align__(16) u16 Ks[2 * 32 * 128];
  __shared__ __align__(16) u16 Vts[2 * 128 * 32];
  __shared__ __align__(16) u16 Plds[4 * 16 * 32];

  const int qb = (int)gridDim.x - 1 - (int)blockIdx.x;  // big blocks first
  const int h = blockIdx.y;
  const int kvh = h >> 2;
  const int tid = threadIdx.x;
  const int w = tid >> 6, l = tid & 63;
  const int g = l >> 4, m = l & 15;
  const int t0 = qb * 64;

  const u16* kbase = Kp + (size_t)kvh * T_LEN * HD;
  const u16* vbase = Vtp + (size_t)kvh * HD * T_LEN;

  // ---- stage Q tile (swizzle: 16B granule ^ (row&7)) ----
  {
    const u16* qbase = Qp + ((size_t)h * T_LEN + t0) * HD;
#pragma unroll
    for (int p = 0; p < 4; ++p) {
      const int row = p * 16 + w * 4 + (l >> 4);
      const int gr = (l & 15) ^ (row & 7);
      gll16(qbase + row * 128 + gr * 8, Qs + p * 2048 + w * 512 + l * 8);
    }
  }
  // ---- stage K (swz ^(row&7)) + Vt (swz ^((d>>1)&3)) for tile jt -> buf b
#define STAGE_KV(jt, b)                                                        \
  {                                                                            \
    _Pragma("unroll") for (int p = 0; p < 2; ++p) {                            \
      const int krow = p * 16 + w * 4 + (l >> 4);                              \
      const int kg = (l & 15) ^ (krow & 7);                                    \
      gll16(kbase + (size_t)((jt) * 32 + krow) * 128 + kg * 8,                 \
            Ks + (b) * 4096 + p * 2048 + w * 512 + l * 8);                     \
      const int dv = p * 64 + w * 16 + (l >> 2);                               \
      const int vg = (l & 3) ^ ((dv >> 1) & 3);                                \
      gll16(vbase + (size_t)dv * T_LEN + (jt) * 32 + vg * 8,                   \
            Vts + (b) * 4096 + p * 2048 + w * 512 + l * 8);                    \
    }                                                                          \
  }

  STAGE_KV(0, 0);
  __syncthreads();

  // ---- hoist Q B-fragments: rows w*16+m, k-granules kk*4+g ----
  bf16x8 qf[4];
  {
    const u16* qr = Qs + (w * 16 + m) * 128;
#pragma unroll
    for (int kk = 0; kk < 4; ++kk)
      qf[kk] = *(const bf16x8*)(qr + (((kk * 4 + g) ^ (m & 7)) * 8));
  }

  f32x4 o[8];
#pragma unroll
  for (int n = 0; n < 8; ++n) o[n] = (f32x4){0.f, 0.f, 0.f, 0.f};
  float mrun = -1e30f, lrun = 0.f;
  u16* pl = Plds + w * 512;  // per-wave P bounce [16 m][32 kv]

  const int NT = 2 * (qb + 1);
  for (int jt = 0; jt < NT; ++jt) {
    const int b = jt & 1;
    if (jt + 1 < NT) STAGE_KV(jt + 1, b ^ 1);

    // ---- S^T = K @ Q^T ----
    f32x4 s[2];
    s[0] = (f32x4){0.f, 0.f, 0.f, 0.f};
    s[1] = (f32x4){0.f, 0.f, 0.f, 0.f};
#pragma unroll
    for (int f = 0; f < 2; ++f) {
      const u16* kr = Ks + b * 4096 + (f * 16 + m) * 128;
#pragma unroll
      for (int kk = 0; kk < 4; ++kk) {
        bf16x8 kf = *(const bf16x8*)(kr + (((kk * 4 + g) ^ (m & 7)) * 8));
        s[f] = __builtin_amdgcn_mfma_f32_16x16x32_bf16(kf, qf[kk], s[f], 0, 0, 0);
      }
    }

    // ---- causal mask (only last two tiles can clip) ----
    if (jt >= NT - 2) {
      const int qg = t0 + w * 16 + m;
      const int kvb = jt * 32 + g * 4;
#pragma unroll
      for (int f = 0; f < 2; ++f)
#pragma unroll
        for (int r = 0; r < 4; ++r)
          if (kvb + f * 16 + r > qg) s[f][r] = -1e30f;
    }

    // ---- online softmax (stats per q-row m; 2 shfl_xor across groups) ----
    float pm = fmaxf(fmaxf(fmaxf(s[0][0], s[0][1]), fmaxf(s[0][2], s[0][3])),
                     fmaxf(fmaxf(s[1][0], s[1][1]), fmaxf(s[1][2], s[1][3])));
    pm = fmaxf(pm, __shfl_xor(pm, 16));
    pm = fmaxf(pm, __shfl_xor(pm, 32));
    const float mn = fmaxf(mrun, pm);
    const float sc = __expf(mrun - mn);
    mrun = mn;
    float ps = 0.f;
#pragma unroll
    for (int f = 0; f < 2; ++f)
#pragma unroll
      for (int r = 0; r < 4; ++r) {
        s[f][r] = __expf(s[f][r] - mn);
        ps += s[f][r];
      }
    ps += __shfl_xor(ps, 16);
    ps += __shfl_xor(ps, 32);
    lrun = lrun * sc + ps;

    // ---- P -> LDS bounce (slot swizzle ^(m>>1); wave-private, no barrier)
    {
      const u32 a0 = (u32)f2b(s[0][0]) | ((u32)f2b(s[0][1]) << 16);
      const u32 a1 = (u32)f2b(s[0][2]) | ((u32)f2b(s[0][3]) << 16);
      const u32 b0 = (u32)f2b(s[1][0]) | ((u32)f2b(s[1][1]) << 16);
      const u32 b1 = (u32)f2b(s[1][2]) | ((u32)f2b(s[1][3]) << 16);
      *(uint2*)(pl + m * 32 + ((g ^ (m >> 1)) * 4)) = make_uint2(a0, a1);
      *(uint2*)(pl + m * 32 + (((g + 4) ^ (m >> 1)) * 4)) = make_uint2(b0, b1);
    }

    // ---- rescale O by per-row factor ----
    f32x4 scr;
#pragma unroll
    for (int r = 0; r < 4; ++r) scr[r] = __shfl(sc, g * 4 + r);
#pragma unroll
    for (int n = 0; n < 8; ++n) o[n] *= scr;

    // ---- read P A-fragment (k octet g*8..+7 = logical slots 2g, 2g+1) ----
    bf16x8 pa;
    {
      const uint2 lo = *(const uint2*)(pl + m * 32 + (((2 * g) ^ (m >> 1)) * 4));
      const uint2 hi =
          *(const uint2*)(pl + m * 32 + (((2 * g + 1) ^ (m >> 1)) * 4));
      union { u32 u[4]; bf16x8 v; } pu;
      pu.u[0] = lo.x; pu.u[1] = lo.y; pu.u[2] = hi.x; pu.u[3] = hi.y;
      pa = pu.v;
    }

    // ---- PV: O[16 q][128 d] += P @ V (B-frag from Vt [d][kv]) ----
#pragma unroll
    for (int n = 0; n < 8; ++n) {
      const int dd = n * 16 + m;
      bf16x8 vf = *(const bf16x8*)(Vts + b * 4096 + dd * 32 +
                                   ((g ^ ((dd >> 1) & 3)) * 8));
      o[n] = __builtin_amdgcn_mfma_f32_16x16x32_bf16(pa, vf, o[n], 0, 0, 0);
    }
    __syncthreads();
  }

  // ---- epilogue: normalize rows, write bf16 [t][h*128+d] ----
  float li[4];
#pragma unroll
  for (int r = 0; r < 4; ++r) li[r] = 1.f / __shfl(lrun, g * 4 + r);
  u16* ob = outB + (size_t)(t0 + w * 16 + g * 4) * HIDDEN + h * HD + m;
#pragma unroll
  for (int n = 0; n < 8; ++n)
#pragma unroll
    for (int r = 0; r < 4; ++r)
      ob[(size_t)r * HIDDEN + n * 16] = f2b(o[n][r] * li[r]);
}

// ---------------------------------------------------------------------------
extern "C" void kernel_launch(void* const* d_in, const int* in_sizes, int n_in,
                              void* d_out, int out_size, void* d_ws,
                              size_t ws_size, hipStream_t stream) {
  const float* hidden = (const float*)d_in[0];
  const int* positions = (const int*)d_in[1];
  const float* w_qkv = (const float*)d_in[2];
  const float* w_o = (const float*)d_in[3];
  const float* q_norm_w = (const float*)d_in[4];
  const float* k_norm_w = (const float*)d_in[5];
  float* out = (float*)d_out;

  // workspace layout (~176 MB); Qp aliases hiddenB (dead after GEMM1)
  u16* hiddenB = (u16*)d_ws;                                // 16.8 MB
  u16* Qp = hiddenB;                                        // alias
  u16* wqkvT = hiddenB + (size_t)T_LEN * HIDDEN;            // 50.3 MB
  u16* woT = wqkvT + (size_t)QKV_N * HIDDEN;                // 33.6 MB
  float* qkv = (float*)(woT + (size_t)HIDDEN * HIDDEN);     // 50.3 MB
  u16* attnB = (u16*)(qkv + (size_t)T_LEN * QKV_N);         // 16.8 MB
  u16* Kp = attnB + (size_t)T_LEN * HIDDEN;                 // 4.2 MB
  u16* Vtp = Kp + (size_t)N_KV * T_LEN * HD;                // 4.2 MB

  // prep
  cast_bf16_kernel<<<(T_LEN * HIDDEN) / 1024, 256, 0, stream>>>(hidden, hiddenB);
  transpose_cast_kernel<<<dim3(QKV_N / 32, HIDDEN / 32), 256, 0, stream>>>(
      w_qkv, wqkvT, HIDDEN, QKV_N);
  transpose_cast_kernel<<<dim3(HIDDEN / 32, HIDDEN / 32), 256, 0, stream>>>(
      w_o, woT, HIDDEN, HIDDEN);

  // 1) qkv = hidden @ w_qkv
  gemm_bf16_kernel<<<dim3(QKV_N / 128, T_LEN / 128), 256, 0, stream>>>(
      hiddenB, wqkvT, qkv, T_LEN, QKV_N, HIDDEN);
  // 2) RMSNorm + RoPE -> packed bf16 Q/K; V transpose -> Vtp
  normrope_pack_kernel<<<dim3(T_LEN, N_HEADS + N_KV), 128, 0, stream>>>(
      qkv, positions, q_norm_w, k_norm_w, Qp, Kp);
  vtrans_kernel<<<dim3(T_LEN / 32, N_KV), 256, 0, stream>>>(qkv, Vtp);
  // 3) MFMA causal GQA flash attention -> bf16 [t][h*128+d]
  attn3_kernel<<<dim3(32, N_HEADS), 256, 0, stream>>>(Qp, Kp, Vtp, attnB);
  // 4) out = attn @ w_o
  gemm_bf16_kernel<<<dim3(HIDDEN / 128, T_LEN / 128), 256, 0, stream>>>(
      attnB, woT, out, T_LEN, HIDDEN, HIDDEN);
}

// Round 7
// 426.688 us; speedup vs baseline: 8.9133x; 1.1371x over previous
//
#include <hip/hip_runtime.h>
#include <math.h>

#define HIDDEN 4096
#define QKV_N 6144      // (32 + 2*8) * 128
#define T_LEN 2048
#define HD 128
#define N_HEADS 32
#define N_KV 8
#define SCALE 0.08838834764831845f  // 128^-0.5

typedef unsigned short u16;
typedef unsigned int u32;
typedef __attribute__((ext_vector_type(8))) short bf16x8;
typedef __attribute__((ext_vector_type(4))) float f32x4;

// fp32 -> bf16 round-to-nearest-even
__device__ __forceinline__ u16 f2b(float x) {
  u32 u = __builtin_bit_cast(u32, x);
  u += 0x7fffu + ((u >> 16) & 1u);
  return (u16)(u >> 16);
}

typedef const __attribute__((address_space(1))) void* gas_ptr;
typedef __attribute__((address_space(3))) void* las_ptr;
__device__ __forceinline__ void gll16(const void* g, void* l) {
  __builtin_amdgcn_global_load_lds((gas_ptr)g, (las_ptr)l, 16, 0, 0);
}

// ---------------------------------------------------------------------------
// elementwise fp32 -> bf16 cast (4 elems/thread)
// ---------------------------------------------------------------------------
__global__ __launch_bounds__(256) void cast_bf16_kernel(
    const float* __restrict__ in, u16* __restrict__ out) {
  const size_t i = ((size_t)blockIdx.x * 256 + threadIdx.x) * 4;
  f32x4 v = *(const f32x4*)(in + i);
  ushort4 o;
  o.x = f2b(v[0]); o.y = f2b(v[1]); o.z = f2b(v[2]); o.w = f2b(v[3]);
  *(ushort4*)(out + i) = o;
}

// ---------------------------------------------------------------------------
// W [K][N] fp32 -> WT [N][K] bf16 (32x32 LDS tile transpose)
// ---------------------------------------------------------------------------
__global__ __launch_bounds__(256) void transpose_cast_kernel(
    const float* __restrict__ W, u16* __restrict__ WT, int K, int N) {
  __shared__ float t[32][33];
  const int n0 = blockIdx.x * 32, k0 = blockIdx.y * 32;
  const int c = threadIdx.x & 31;
  const int r0 = threadIdx.x >> 5;
#pragma unroll
  for (int j = 0; j < 4; ++j) {
    const int r = r0 + 8 * j;
    t[c][r] = W[(size_t)(k0 + r) * N + n0 + c];
  }
  __syncthreads();
#pragma unroll
  for (int j = 0; j < 4; ++j) {
    const int n = r0 + 8 * j;
    WT[(size_t)(n0 + n) * K + k0 + c] = f2b(t[n][c]);
  }
}

// ---------------------------------------------------------------------------
// 8-phase 256xBN bf16 MFMA GEMM (T2 swizzle + T3/T4 counted vmcnt + T5).
// C_f32[M][N] = A_bf16[M][K] @ BT_bf16[N][K]^T.  BM=256, BK=64, 512 thr
// (8 waves 2Mx4N; per-wave C = 128 x BN/4). LDS k-split planes
// [buf][khalf][rows][32] so each stage unit (A-khalf / B-khalf) is
// contiguous; stage via global_load_lds w/ pre-swizzled source
// (octet ^= (row>>1)&3), ds_read with same XOR -> conflict-free.
// Stage stream runs 4 units ahead; vmcnt(NV) at phases 2,4 lands exactly
// the 2 units the next phases read (never drains to 0 mid-loop).
// ---------------------------------------------------------------------------
template <int BN>
__global__ __launch_bounds__(512, 2) void gemm256_kernel(
    const u16* __restrict__ A, const u16* __restrict__ BT,
    float* __restrict__ C, int M, int N, int K) {
  constexpr int WCOLS = BN / 4;     // 64 or 32
  constexpr int NF = WCOLS / 16;    // 4 or 2  (N-frags per wave)
  constexpr int NF2 = NF / 2;       // 2 or 1  (N-frags per phase)
  constexpr int BLOADS = BN / 128;  // 2 or 1  (gll16 per B unit per thread)
  __shared__ __align__(16) u16 As[2][2][256 * 32];
  __shared__ __align__(16) u16 Bs[2][2][BN * 32];

  const int tid = threadIdx.x;
  const int w = tid >> 6, l = tid & 63;
  const int wr = w >> 2, wc = w & 3;
  const int m = l & 15, g = l >> 4;
  const int bm = blockIdx.y * 256, bn = blockIdx.x * BN;
  const int NT = K >> 6;

  // staging per-thread constants (slot s -> row r = s>>2, octet o = s&3)
  size_t gA[2]; int sA[2];
  size_t gB[2]; int sB[2];
#pragma unroll
  for (int i = 0; i < 2; ++i) {
    const int s = i * 512 + tid;
    const int r = s >> 2, o = s & 3;
    sA[i] = s * 8;
    gA[i] = (size_t)(bm + r) * K + (o ^ ((r >> 1) & 3)) * 8;
  }
#pragma unroll
  for (int i = 0; i < BLOADS; ++i) {
    const int s = i * 512 + tid;
    const int r = s >> 2, o = s & 3;
    sB[i] = s * 8;
    gB[i] = (size_t)(bn + r) * K + (o ^ ((r >> 1) & 3)) * 8;
  }

  // fragment read offset within a khalf plane (elems); rows 16-aligned base
  const int foff = m * 32 + ((g ^ ((m >> 1) & 3)) * 8);
  const int abase = wr * 128 * 32;
  const int bbase = wc * WCOLS * 32;

#define STAGE_A(tile, kh)                                                      \
  {                                                                            \
    const size_t kofs = (size_t)(tile) * 64 + (kh) * 32;                       \
    u16* dst = &As[(tile) & 1][kh][0];                                         \
    gll16(A + gA[0] + kofs, dst + sA[0]);                                      \
    gll16(A + gA[1] + kofs, dst + sA[1]);                                      \
  }
#define STAGE_B(tile, kh)                                                      \
  {                                                                            \
    const size_t kofs = (size_t)(tile) * 64 + (kh) * 32;                       \
    u16* dst = &Bs[(tile) & 1][kh][0];                                         \
    gll16(BT + gB[0] + kofs, dst + sB[0]);                                     \
    if constexpr (BLOADS > 1) gll16(BT + gB[1] + kofs, dst + sB[1]);           \
  }
#define VM_COUNTED()                                                           \
  {                                                                            \
    if constexpr (BN == 256)                                                   \
      asm volatile("s_waitcnt vmcnt(4)" ::: "memory");                         \
    else                                                                       \
      asm volatile("s_waitcnt vmcnt(3)" ::: "memory");                         \
  }
// phase j (qn=j&1, kh=j>>1), reading buf b; optionally stage unit j of tile tn
// VM: 0 = vmcnt(0), 1 = counted, 2 = none  (applied only at odd phases)
#define PHASE(j, b, DO_STAGE, tn, VM)                                          \
  {                                                                            \
    constexpr int qn = (j) & 1, kh = (j) >> 1;                                 \
    if constexpr (qn == 0) {                                                   \
      _Pragma("unroll") for (int fm = 0; fm < 8; ++fm)                         \
          af[fm] = *(const bf16x8*)(&As[b][kh][abase + fm * 512 + foff]);      \
    }                                                                          \
    bf16x8 bf[NF2];                                                            \
    _Pragma("unroll") for (int fn = 0; fn < NF2; ++fn)                         \
        bf[fn] =                                                               \
        *(const bf16x8*)(&Bs[b][kh][bbase + (qn * NF2 + fn) * 512 + foff]);    \
    if constexpr (DO_STAGE) {                                                  \
      if constexpr ((j) == 0) STAGE_A(tn, 0);                                  \
      if constexpr ((j) == 1) STAGE_B(tn, 0);                                  \
      if constexpr ((j) == 2) STAGE_A(tn, 1);                                  \
      if constexpr ((j) == 3) STAGE_B(tn, 1);                                  \
    }                                                                          \
    asm volatile("" ::: "memory");                                             \
    __builtin_amdgcn_s_barrier();                                              \
    asm volatile("" ::: "memory");                                             \
    __builtin_amdgcn_s_setprio(1);                                             \
    _Pragma("unroll") for (int fm = 0; fm < 8; ++fm)                           \
        _Pragma("unroll") for (int fn = 0; fn < NF2; ++fn)                     \
        acc[fm][qn * NF2 + fn] = __builtin_amdgcn_mfma_f32_16x16x32_bf16(      \
            af[fm], bf[fn], acc[fm][qn * NF2 + fn], 0, 0, 0);                  \
    __builtin_amdgcn_s_setprio(0);                                             \
    asm volatile("" ::: "memory");                                             \
    if constexpr (((j) & 1) && (VM) == 0)                                      \
      asm volatile("s_waitcnt vmcnt(0)" ::: "memory");                         \
    if constexpr (((j) & 1) && (VM) == 1) VM_COUNTED();                        \
    __builtin_amdgcn_s_barrier();                                              \
    asm volatile("" ::: "memory");                                             \
  }

  f32x4 acc[8][NF];
#pragma unroll
  for (int i = 0; i < 8; ++i)
#pragma unroll
    for (int j = 0; j < NF; ++j) acc[i][j] = (f32x4){0.f, 0.f, 0.f, 0.f};

  // prologue: stage tile 0 (units 0..3), land units 0,1 (leave 2 in flight)
  STAGE_A(0, 0); STAGE_B(0, 0); STAGE_A(0, 1); STAGE_B(0, 1);
  VM_COUNTED();
  __builtin_amdgcn_s_barrier();
  asm volatile("" ::: "memory");

  bf16x8 af[8];
  for (int t = 0; t < NT - 1; ++t) {
    const int b = t & 1, tn = t + 1;
    PHASE(0, b, true, tn, 1);
    PHASE(1, b, true, tn, 1);
    PHASE(2, b, true, tn, 1);
    PHASE(3, b, true, tn, 1);
  }
  {  // tail K-tile: no staging; phase 1 drains the last 2 units
    const int b = (NT - 1) & 1;
    PHASE(0, b, false, 0, 2);
    PHASE(1, b, false, 0, 0);
    PHASE(2, b, false, 0, 2);
    PHASE(3, b, false, 0, 2);
  }
#undef PHASE
#undef VM_COUNTED
#undef STAGE_B
#undef STAGE_A

  // C/D layout (verified r5): row = base + g*4 + r, col = base + m
#pragma unroll
  for (int fm = 0; fm < 8; ++fm) {
    const int row = bm + wr * 128 + fm * 16 + g * 4;
#pragma unroll
    for (int fn = 0; fn < NF; ++fn) {
      const int col = bn + wc * WCOLS + fn * 16 + m;
      float* cp = C + (size_t)row * N + col;
#pragma unroll
      for (int r = 0; r < 4; ++r) cp[(size_t)r * N] = acc[fm][fn][r];
    }
  }
}

// ---------------------------------------------------------------------------
// Fused per-head RMSNorm + partial RoPE -> packed bf16.
// Q (scale folded): Qp[h][t][128]; K: Kp[kvh][t][128]. grid (T, 40), 128 thr.
// ---------------------------------------------------------------------------
__global__ __launch_bounds__(128) void normrope_pack_kernel(
    const float* __restrict__ qkv, const int* __restrict__ positions,
    const float* __restrict__ qw, const float* __restrict__ kw,
    u16* __restrict__ Qp, u16* __restrict__ Kp) {
  const int t = blockIdx.x;
  const int hh = blockIdx.y;  // 0..39
  const int d = threadIdx.x;  // 0..127
  const bool isq = hh < N_HEADS;
  const int col = isq ? hh * HD : HIDDEN + (hh - N_HEADS) * HD;
  const float* row = qkv + (size_t)t * QKV_N + col;
  const float* w = isq ? qw : kw;

  float x = row[d];
  float ss = x * x;
#pragma unroll
  for (int off = 32; off >= 1; off >>= 1) ss += __shfl_xor(ss, off);
  __shared__ float wsum[2];
  __shared__ float xs[128];
  if ((d & 63) == 0) wsum[d >> 6] = ss;
  __syncthreads();
  const float tot = wsum[0] + wsum[1];
  const float inv = rsqrtf(tot * (1.f / 128.f) + 1e-6f);
  const float xn = x * inv * w[d];
  xs[d] = xn;
  __syncthreads();

  float outv;
  if (d < 64) {
    const int idx = d & 31;
    const float invf = powf(1.0e6f, -(float)idx * (1.0f / 32.0f));
    const float fr = (float)positions[t] * invf;
    const float c = cosf(fr), s = sinf(fr);
    const float x1 = xs[idx], x2 = xs[idx + 32];
    outv = (d < 32) ? (x1 * c - x2 * s) : (x2 * c + x1 * s);
  } else {
    outv = xn;
  }
  if (isq) {
    Qp[((size_t)hh * T_LEN + t) * HD + d] = f2b(outv * SCALE);
  } else {
    Kp[((size_t)(hh - N_HEADS) * T_LEN + t) * HD + d] = f2b(outv);
  }
}

// ---------------------------------------------------------------------------
// V transpose+cast: qkv V region fp32 [t][d] -> Vtp[kvh][d][t] bf16.
// ---------------------------------------------------------------------------
__global__ __launch_bounds__(256) void vtrans_kernel(
    const float* __restrict__ qkv, u16* __restrict__ Vtp) {
  __shared__ float tile[32][132];
  const int t0 = blockIdx.x * 32;
  const int kvh = blockIdx.y;
  const int tv = threadIdx.x >> 3;          // 0..31
  const int c0 = (threadIdx.x & 7) * 16;    // 0..112
  const float* src =
      qkv + (size_t)(t0 + tv) * QKV_N + (HIDDEN + 1024) + kvh * HD + c0;
#pragma unroll
  for (int u = 0; u < 4; ++u)
    *(f32x4*)&tile[tv][c0 + 4 * u] = *(const f32x4*)(src + 4 * u);
  __syncthreads();
  const int dd = threadIdx.x >> 1;   // 0..127
  const int half = threadIdx.x & 1;  // 0,1
  u16 buf[16];
#pragma unroll
  for (int p = 0; p < 16; ++p) buf[p] = f2b(tile[half * 16 + p][dd]);
  u16* dst = Vtp + ((size_t)kvh * HD + dd) * T_LEN + t0 + half * 16;
  *(uint4*)dst = *(uint4*)&buf[0];
  *(uint4*)(dst + 8) = *(uint4*)&buf[8];
}

// ---------------------------------------------------------------------------
// MFMA causal GQA flash attention. grid (32 qb, 32 h), 256 thr (4 waves).
// ---------------------------------------------------------------------------
__global__ __launch_bounds__(256, 3) void attn3_kernel(
    const u16* __restrict__ Qp, const u16* __restrict__ Kp,
    const u16* __restrict__ Vtp, u16* __restrict__ outB) {
  __shared__ __align__(16) u16 Qs[64 * 128];
  __shared__ __align__(16) u16 Ks[2 * 32 * 128];
  __shared__ __align__(16) u16 Vts[2 * 128 * 32];
  __shared__ __align__(16) u16 Plds[4 * 16 * 32];

  const int qb = (int)gridDim.x - 1 - (int)blockIdx.x;  // big blocks first
  const int h = blockIdx.y;
  const int kvh = h >> 2;
  const int tid = threadIdx.x;
  const int w = tid >> 6, l = tid & 63;
  const int g = l >> 4, m = l & 15;
  const int t0 = qb * 64;

  const u16* kbase = Kp + (size_t)kvh * T_LEN * HD;
  const u16* vbase = Vtp + (size_t)kvh * HD * T_LEN;

  // ---- stage Q tile (swizzle: 16B granule ^ (row&7)) ----
  {
    const u16* qbase = Qp + ((size_t)h * T_LEN + t0) * HD;
#pragma unroll
    for (int p = 0; p < 4; ++p) {
      const int row = p * 16 + w * 4 + (l >> 4);
      const int gr = (l & 15) ^ (row & 7);
      gll16(qbase + row * 128 + gr * 8, Qs + p * 2048 + w * 512 + l * 8);
    }
  }
#define STAGE_KV(jt, b)                                                        \
  {                                                                            \
    _Pragma("unroll") for (int p = 0; p < 2; ++p) {                            \
      const int krow = p * 16 + w * 4 + (l >> 4);                              \
      const int kg = (l & 15) ^ (krow & 7);                                    \
      gll16(kbase + (size_t)((jt) * 32 + krow) * 128 + kg * 8,                 \
            Ks + (b) * 4096 + p * 2048 + w * 512 + l * 8);                     \
      const int dv = p * 64 + w * 16 + (l >> 2);                               \
      const int vg = (l & 3) ^ ((dv >> 1) & 3);                                \
      gll16(vbase + (size_t)dv * T_LEN + (jt) * 32 + vg * 8,                   \
            Vts + (b) * 4096 + p * 2048 + w * 512 + l * 8);                    \
    }                                                                          \
  }

  STAGE_KV(0, 0);
  __syncthreads();

  // ---- hoist Q B-fragments ----
  bf16x8 qf[4];
  {
    const u16* qr = Qs + (w * 16 + m) * 128;
#pragma unroll
    for (int kk = 0; kk < 4; ++kk)
      qf[kk] = *(const bf16x8*)(qr + (((kk * 4 + g) ^ (m & 7)) * 8));
  }

  f32x4 o[8];
#pragma unroll
  for (int n = 0; n < 8; ++n) o[n] = (f32x4){0.f, 0.f, 0.f, 0.f};
  float mrun = -1e30f, lrun = 0.f;
  u16* pl = Plds + w * 512;  // per-wave P bounce [16 m][32 kv]

  const int NT = 2 * (qb + 1);
  for (int jt = 0; jt < NT; ++jt) {
    const int b = jt & 1;
    if (jt + 1 < NT) STAGE_KV(jt + 1, b ^ 1);

    // ---- S^T = K @ Q^T ----
    f32x4 s[2];
    s[0] = (f32x4){0.f, 0.f, 0.f, 0.f};
    s[1] = (f32x4){0.f, 0.f, 0.f, 0.f};
#pragma unroll
    for (int f = 0; f < 2; ++f) {
      const u16* kr = Ks + b * 4096 + (f * 16 + m) * 128;
#pragma unroll
      for (int kk = 0; kk < 4; ++kk) {
        bf16x8 kf = *(const bf16x8*)(kr + (((kk * 4 + g) ^ (m & 7)) * 8));
        s[f] = __builtin_amdgcn_mfma_f32_16x16x32_bf16(kf, qf[kk], s[f], 0, 0, 0);
      }
    }

    // ---- causal mask (only last two tiles can clip) ----
    if (jt >= NT - 2) {
      const int qg = t0 + w * 16 + m;
      const int kvb = jt * 32 + g * 4;
#pragma unroll
      for (int f = 0; f < 2; ++f)
#pragma unroll
        for (int r = 0; r < 4; ++r)
          if (kvb + f * 16 + r > qg) s[f][r] = -1e30f;
    }

    // ---- online softmax ----
    float pm = fmaxf(fmaxf(fmaxf(s[0][0], s[0][1]), fmaxf(s[0][2], s[0][3])),
                     fmaxf(fmaxf(s[1][0], s[1][1]), fmaxf(s[1][2], s[1][3])));
    pm = fmaxf(pm, __shfl_xor(pm, 16));
    pm = fmaxf(pm, __shfl_xor(pm, 32));
    const float mn = fmaxf(mrun, pm);
    const float sc = __expf(mrun - mn);
    mrun = mn;
    float ps = 0.f;
#pragma unroll
    for (int f = 0; f < 2; ++f)
#pragma unroll
      for (int r = 0; r < 4; ++r) {
        s[f][r] = __expf(s[f][r] - mn);
        ps += s[f][r];
      }
    ps += __shfl_xor(ps, 16);
    ps += __shfl_xor(ps, 32);
    lrun = lrun * sc + ps;

    // ---- P -> LDS bounce (wave-private) ----
    {
      const u32 a0 = (u32)f2b(s[0][0]) | ((u32)f2b(s[0][1]) << 16);
      const u32 a1 = (u32)f2b(s[0][2]) | ((u32)f2b(s[0][3]) << 16);
      const u32 b0 = (u32)f2b(s[1][0]) | ((u32)f2b(s[1][1]) << 16);
      const u32 b1 = (u32)f2b(s[1][2]) | ((u32)f2b(s[1][3]) << 16);
      *(uint2*)(pl + m * 32 + ((g ^ (m >> 1)) * 4)) = make_uint2(a0, a1);
      *(uint2*)(pl + m * 32 + (((g + 4) ^ (m >> 1)) * 4)) = make_uint2(b0, b1);
    }

    // ---- rescale O ----
    f32x4 scr;
#pragma unroll
    for (int r = 0; r < 4; ++r) scr[r] = __shfl(sc, g * 4 + r);
#pragma unroll
    for (int n = 0; n < 8; ++n) o[n] *= scr;

    // ---- read P A-fragment ----
    bf16x8 pa;
    {
      const uint2 lo = *(const uint2*)(pl + m * 32 + (((2 * g) ^ (m >> 1)) * 4));
      const uint2 hi =
          *(const uint2*)(pl + m * 32 + (((2 * g + 1) ^ (m >> 1)) * 4));
      union { u32 u[4]; bf16x8 v; } pu;
      pu.u[0] = lo.x; pu.u[1] = lo.y; pu.u[2] = hi.x; pu.u[3] = hi.y;
      pa = pu.v;
    }

    // ---- PV ----
#pragma unroll
    for (int n = 0; n < 8; ++n) {
      const int dd = n * 16 + m;
      bf16x8 vf = *(const bf16x8*)(Vts + b * 4096 + dd * 32 +
                                   ((g ^ ((dd >> 1) & 3)) * 8));
      o[n] = __builtin_amdgcn_mfma_f32_16x16x32_bf16(pa, vf, o[n], 0, 0, 0);
    }
    __syncthreads();
  }

  // ---- epilogue ----
  float li[4];
#pragma unroll
  for (int r = 0; r < 4; ++r) li[r] = 1.f / __shfl(lrun, g * 4 + r);
  u16* ob = outB + (size_t)(t0 + w * 16 + g * 4) * HIDDEN + h * HD + m;
#pragma unroll
  for (int n = 0; n < 8; ++n)
#pragma unroll
    for (int r = 0; r < 4; ++r)
      ob[(size_t)r * HIDDEN + n * 16] = f2b(o[n][r] * li[r]);
}

// ---------------------------------------------------------------------------
extern "C" void kernel_launch(void* const* d_in, const int* in_sizes, int n_in,
                              void* d_out, int out_size, void* d_ws,
                              size_t ws_size, hipStream_t stream) {
  const float* hidden = (const float*)d_in[0];
  const int* positions = (const int*)d_in[1];
  const float* w_qkv = (const float*)d_in[2];
  const float* w_o = (const float*)d_in[3];
  const float* q_norm_w = (const float*)d_in[4];
  const float* k_norm_w = (const float*)d_in[5];
  float* out = (float*)d_out;

  // workspace layout (~176 MB); Qp aliases hiddenB (dead after GEMM1)
  u16* hiddenB = (u16*)d_ws;                                // 16.8 MB
  u16* Qp = hiddenB;                                        // alias
  u16* wqkvT = hiddenB + (size_t)T_LEN * HIDDEN;            // 50.3 MB
  u16* woT = wqkvT + (size_t)QKV_N * HIDDEN;                // 33.6 MB
  float* qkv = (float*)(woT + (size_t)HIDDEN * HIDDEN);     // 50.3 MB
  u16* attnB = (u16*)(qkv + (size_t)T_LEN * QKV_N);         // 16.8 MB
  u16* Kp = attnB + (size_t)T_LEN * HIDDEN;                 // 4.2 MB
  u16* Vtp = Kp + (size_t)N_KV * T_LEN * HD;                // 4.2 MB

  // prep
  cast_bf16_kernel<<<(T_LEN * HIDDEN) / 1024, 256, 0, stream>>>(hidden, hiddenB);
  transpose_cast_kernel<<<dim3(QKV_N / 32, HIDDEN / 32), 256, 0, stream>>>(
      w_qkv, wqkvT, HIDDEN, QKV_N);
  transpose_cast_kernel<<<dim3(HIDDEN / 32, HIDDEN / 32), 256, 0, stream>>>(
      w_o, woT, HIDDEN, HIDDEN);

  // 1) qkv = hidden @ w_qkv  (8-phase 256x256, grid 24x8)
  gemm256_kernel<256><<<dim3(QKV_N / 256, T_LEN / 256), 512, 0, stream>>>(
      hiddenB, wqkvT, qkv, T_LEN, QKV_N, HIDDEN);
  // 2) RMSNorm + RoPE -> packed bf16 Q/K; V transpose -> Vtp
  normrope_pack_kernel<<<dim3(T_LEN, N_HEADS + N_KV), 128, 0, stream>>>(
      qkv, positions, q_norm_w, k_norm_w, Qp, Kp);
  vtrans_kernel<<<dim3(T_LEN / 32, N_KV), 256, 0, stream>>>(qkv, Vtp);
  // 3) MFMA causal GQA flash attention -> bf16 [t][h*128+d]
  attn3_kernel<<<dim3(32, N_HEADS), 256, 0, stream>>>(Qp, Kp, Vtp, attnB);
  // 4) out = attn @ w_o  (8-phase 256x128, grid 32x8 = 256 blocks)
  gemm256_kernel<128><<<dim3(HIDDEN / 128, T_LEN / 256), 512, 0, stream>>>(
      attnB, woT, out, T_LEN, HIDDEN, HIDDEN);
}

// Round 8
// 365.774 us; speedup vs baseline: 10.3977x; 1.1665x over previous
//
#include <hip/hip_runtime.h>
#include <math.h>

#define HIDDEN 4096
#define QKV_N 6144      // (32 + 2*8) * 128
#define T_LEN 2048
#define HD 128
#define N_HEADS 32
#define N_KV 8
#define SCALE 0.08838834764831845f  // 128^-0.5

typedef unsigned short u16;
typedef unsigned int u32;
typedef __attribute__((ext_vector_type(8))) short bf16x8;
typedef __attribute__((ext_vector_type(4))) float f32x4;

// fp32 -> bf16 round-to-nearest-even
__device__ __forceinline__ u16 f2b(float x) {
  u32 u = __builtin_bit_cast(u32, x);
  u += 0x7fffu + ((u >> 16) & 1u);
  return (u16)(u >> 16);
}

typedef const __attribute__((address_space(1))) void* gas_ptr;
typedef __attribute__((address_space(3))) void* las_ptr;
__device__ __forceinline__ void gll16(const void* g, void* l) {
  __builtin_amdgcn_global_load_lds((gas_ptr)g, (las_ptr)l, 16, 0, 0);
}

// ---------------------------------------------------------------------------
// elementwise fp32 -> bf16 cast (4 elems/thread)
// ---------------------------------------------------------------------------
__global__ __launch_bounds__(256) void cast_bf16_kernel(
    const float* __restrict__ in, u16* __restrict__ out) {
  const size_t i = ((size_t)blockIdx.x * 256 + threadIdx.x) * 4;
  f32x4 v = *(const f32x4*)(in + i);
  ushort4 o;
  o.x = f2b(v[0]); o.y = f2b(v[1]); o.z = f2b(v[2]); o.w = f2b(v[3]);
  *(ushort4*)(out + i) = o;
}

// ---------------------------------------------------------------------------
// W [K][N] fp32 -> WT [N][K] bf16 (32x32 LDS tile transpose)
// ---------------------------------------------------------------------------
__global__ __launch_bounds__(256) void transpose_cast_kernel(
    const float* __restrict__ W, u16* __restrict__ WT, int K, int N) {
  __shared__ float t[32][33];
  const int n0 = blockIdx.x * 32, k0 = blockIdx.y * 32;
  const int c = threadIdx.x & 31;
  const int r0 = threadIdx.x >> 5;
#pragma unroll
  for (int j = 0; j < 4; ++j) {
    const int r = r0 + 8 * j;
    t[c][r] = W[(size_t)(k0 + r) * N + n0 + c];
  }
  __syncthreads();
#pragma unroll
  for (int j = 0; j < 4; ++j) {
    const int n = r0 + 8 * j;
    WT[(size_t)(n0 + n) * K + k0 + c] = f2b(t[n][c]);
  }
}

// ---------------------------------------------------------------------------
// 8-phase 256xBN bf16 MFMA GEMM (T2 swizzle + T3/T4 counted vmcnt + T5).
// ---------------------------------------------------------------------------
template <int BN>
__global__ __launch_bounds__(512, 2) void gemm256_kernel(
    const u16* __restrict__ A, const u16* __restrict__ BT,
    float* __restrict__ C, int M, int N, int K) {
  constexpr int WCOLS = BN / 4;     // 64 or 32
  constexpr int NF = WCOLS / 16;    // 4 or 2  (N-frags per wave)
  constexpr int NF2 = NF / 2;       // 2 or 1  (N-frags per phase)
  constexpr int BLOADS = BN / 128;  // 2 or 1  (gll16 per B unit per thread)
  __shared__ __align__(16) u16 As[2][2][256 * 32];
  __shared__ __align__(16) u16 Bs[2][2][BN * 32];

  const int tid = threadIdx.x;
  const int w = tid >> 6, l = tid & 63;
  const int wr = w >> 2, wc = w & 3;
  const int m = l & 15, g = l >> 4;
  const int bm = blockIdx.y * 256, bn = blockIdx.x * BN;
  const int NT = K >> 6;

  size_t gA[2]; int sA[2];
  size_t gB[2]; int sB[2];
#pragma unroll
  for (int i = 0; i < 2; ++i) {
    const int s = i * 512 + tid;
    const int r = s >> 2, o = s & 3;
    sA[i] = s * 8;
    gA[i] = (size_t)(bm + r) * K + (o ^ ((r >> 1) & 3)) * 8;
  }
#pragma unroll
  for (int i = 0; i < BLOADS; ++i) {
    const int s = i * 512 + tid;
    const int r = s >> 2, o = s & 3;
    sB[i] = s * 8;
    gB[i] = (size_t)(bn + r) * K + (o ^ ((r >> 1) & 3)) * 8;
  }

  const int foff = m * 32 + ((g ^ ((m >> 1) & 3)) * 8);
  const int abase = wr * 128 * 32;
  const int bbase = wc * WCOLS * 32;

#define STAGE_A(tile, kh)                                                      \
  {                                                                            \
    const size_t kofs = (size_t)(tile) * 64 + (kh) * 32;                       \
    u16* dst = &As[(tile) & 1][kh][0];                                         \
    gll16(A + gA[0] + kofs, dst + sA[0]);                                      \
    gll16(A + gA[1] + kofs, dst + sA[1]);                                      \
  }
#define STAGE_B(tile, kh)                                                      \
  {                                                                            \
    const size_t kofs = (size_t)(tile) * 64 + (kh) * 32;                       \
    u16* dst = &Bs[(tile) & 1][kh][0];                                         \
    gll16(BT + gB[0] + kofs, dst + sB[0]);                                     \
    if constexpr (BLOADS > 1) gll16(BT + gB[1] + kofs, dst + sB[1]);           \
  }
#define VM_COUNTED()                                                           \
  {                                                                            \
    if constexpr (BN == 256)                                                   \
      asm volatile("s_waitcnt vmcnt(4)" ::: "memory");                         \
    else                                                                       \
      asm volatile("s_waitcnt vmcnt(3)" ::: "memory");                         \
  }
#define PHASE(j, b, DO_STAGE, tn, VM)                                          \
  {                                                                            \
    constexpr int qn = (j) & 1, kh = (j) >> 1;                                 \
    if constexpr (qn == 0) {                                                   \
      _Pragma("unroll") for (int fm = 0; fm < 8; ++fm)                         \
          af[fm] = *(const bf16x8*)(&As[b][kh][abase + fm * 512 + foff]);      \
    }                                                                          \
    bf16x8 bf[NF2];                                                            \
    _Pragma("unroll") for (int fn = 0; fn < NF2; ++fn)                         \
        bf[fn] =                                                               \
        *(const bf16x8*)(&Bs[b][kh][bbase + (qn * NF2 + fn) * 512 + foff]);    \
    if constexpr (DO_STAGE) {                                                  \
      if constexpr ((j) == 0) STAGE_A(tn, 0);                                  \
      if constexpr ((j) == 1) STAGE_B(tn, 0);                                  \
      if constexpr ((j) == 2) STAGE_A(tn, 1);                                  \
      if constexpr ((j) == 3) STAGE_B(tn, 1);                                  \
    }                                                                          \
    asm volatile("" ::: "memory");                                             \
    __builtin_amdgcn_s_barrier();                                              \
    asm volatile("" ::: "memory");                                             \
    __builtin_amdgcn_s_setprio(1);                                             \
    _Pragma("unroll") for (int fm = 0; fm < 8; ++fm)                           \
        _Pragma("unroll") for (int fn = 0; fn < NF2; ++fn)                     \
        acc[fm][qn * NF2 + fn] = __builtin_amdgcn_mfma_f32_16x16x32_bf16(      \
            af[fm], bf[fn], acc[fm][qn * NF2 + fn], 0, 0, 0);                  \
    __builtin_amdgcn_s_setprio(0);                                             \
    asm volatile("" ::: "memory");                                             \
    if constexpr (((j) & 1) && (VM) == 0)                                      \
      asm volatile("s_waitcnt vmcnt(0)" ::: "memory");                         \
    if constexpr (((j) & 1) && (VM) == 1) VM_COUNTED();                        \
    __builtin_amdgcn_s_barrier();                                              \
    asm volatile("" ::: "memory");                                             \
  }

  f32x4 acc[8][NF];
#pragma unroll
  for (int i = 0; i < 8; ++i)
#pragma unroll
    for (int j = 0; j < NF; ++j) acc[i][j] = (f32x4){0.f, 0.f, 0.f, 0.f};

  STAGE_A(0, 0); STAGE_B(0, 0); STAGE_A(0, 1); STAGE_B(0, 1);
  VM_COUNTED();
  __builtin_amdgcn_s_barrier();
  asm volatile("" ::: "memory");

  bf16x8 af[8];
  for (int t = 0; t < NT - 1; ++t) {
    const int b = t & 1, tn = t + 1;
    PHASE(0, b, true, tn, 1);
    PHASE(1, b, true, tn, 1);
    PHASE(2, b, true, tn, 1);
    PHASE(3, b, true, tn, 1);
  }
  {
    const int b = (NT - 1) & 1;
    PHASE(0, b, false, 0, 2);
    PHASE(1, b, false, 0, 0);
    PHASE(2, b, false, 0, 2);
    PHASE(3, b, false, 0, 2);
  }
#undef PHASE
#undef VM_COUNTED
#undef STAGE_B
#undef STAGE_A

#pragma unroll
  for (int fm = 0; fm < 8; ++fm) {
    const int row = bm + wr * 128 + fm * 16 + g * 4;
#pragma unroll
    for (int fn = 0; fn < NF; ++fn) {
      const int col = bn + wc * WCOLS + fn * 16 + m;
      float* cp = C + (size_t)row * N + col;
#pragma unroll
      for (int r = 0; r < 4; ++r) cp[(size_t)r * N] = acc[fm][fn][r];
    }
  }
}

// ---------------------------------------------------------------------------
// Fused per-head RMSNorm + partial RoPE -> packed bf16.
// ---------------------------------------------------------------------------
__global__ __launch_bounds__(128) void normrope_pack_kernel(
    const float* __restrict__ qkv, const int* __restrict__ positions,
    const float* __restrict__ qw, const float* __restrict__ kw,
    u16* __restrict__ Qp, u16* __restrict__ Kp) {
  const int t = blockIdx.x;
  const int hh = blockIdx.y;  // 0..39
  const int d = threadIdx.x;  // 0..127
  const bool isq = hh < N_HEADS;
  const int col = isq ? hh * HD : HIDDEN + (hh - N_HEADS) * HD;
  const float* row = qkv + (size_t)t * QKV_N + col;
  const float* w = isq ? qw : kw;

  float x = row[d];
  float ss = x * x;
#pragma unroll
  for (int off = 32; off >= 1; off >>= 1) ss += __shfl_xor(ss, off);
  __shared__ float wsum[2];
  __shared__ float xs[128];
  if ((d & 63) == 0) wsum[d >> 6] = ss;
  __syncthreads();
  const float tot = wsum[0] + wsum[1];
  const float inv = rsqrtf(tot * (1.f / 128.f) + 1e-6f);
  const float xn = x * inv * w[d];
  xs[d] = xn;
  __syncthreads();

  float outv;
  if (d < 64) {
    const int idx = d & 31;
    const float invf = powf(1.0e6f, -(float)idx * (1.0f / 32.0f));
    const float fr = (float)positions[t] * invf;
    const float c = cosf(fr), s = sinf(fr);
    const float x1 = xs[idx], x2 = xs[idx + 32];
    outv = (d < 32) ? (x1 * c - x2 * s) : (x2 * c + x1 * s);
  } else {
    outv = xn;
  }
  if (isq) {
    Qp[((size_t)hh * T_LEN + t) * HD + d] = f2b(outv * SCALE);
  } else {
    Kp[((size_t)(hh - N_HEADS) * T_LEN + t) * HD + d] = f2b(outv);
  }
}

// ---------------------------------------------------------------------------
// V transpose+cast: qkv V region fp32 [t][d] -> Vtp[kvh][d][t] bf16.
// ---------------------------------------------------------------------------
__global__ __launch_bounds__(256) void vtrans_kernel(
    const float* __restrict__ qkv, u16* __restrict__ Vtp) {
  __shared__ float tile[32][132];
  const int t0 = blockIdx.x * 32;
  const int kvh = blockIdx.y;
  const int tv = threadIdx.x >> 3;          // 0..31
  const int c0 = (threadIdx.x & 7) * 16;    // 0..112
  const float* src =
      qkv + (size_t)(t0 + tv) * QKV_N + (HIDDEN + 1024) + kvh * HD + c0;
#pragma unroll
  for (int u = 0; u < 4; ++u)
    *(f32x4*)&tile[tv][c0 + 4 * u] = *(const f32x4*)(src + 4 * u);
  __syncthreads();
  const int dd = threadIdx.x >> 1;   // 0..127
  const int half = threadIdx.x & 1;  // 0,1
  u16 buf[16];
#pragma unroll
  for (int p = 0; p < 16; ++p) buf[p] = f2b(tile[half * 16 + p][dd]);
  u16* dst = Vtp + ((size_t)kvh * HD + dd) * T_LEN + t0 + half * 16;
  *(uint4*)dst = *(uint4*)&buf[0];
  *(uint4*)(dst + 8) = *(uint4*)&buf[8];
}

// ---------------------------------------------------------------------------
// MFMA causal GQA flash attention, work-balanced pairing + defer-max + T5.
// grid (16, 32): block bx handles Q-tiles qb = 31-bx then bx (NT sum = 66
// KV-tiles = constant -> no load-imbalance tail). 256 thr (4 waves).
// ---------------------------------------------------------------------------
__global__ __launch_bounds__(256, 3) void attn4_kernel(
    const u16* __restrict__ Qp, const u16* __restrict__ Kp,
    const u16* __restrict__ Vtp, u16* __restrict__ outB) {
  __shared__ __align__(16) u16 Qs[64 * 128];
  __shared__ __align__(16) u16 Ks[2 * 32 * 128];
  __shared__ __align__(16) u16 Vts[2 * 128 * 32];
  __shared__ __align__(16) u16 Plds[4 * 16 * 32];

  const int bx = blockIdx.x;  // 0..15
  const int h = blockIdx.y;
  const int kvh = h >> 2;
  const int tid = threadIdx.x;
  const int w = tid >> 6, l = tid & 63;
  const int g = l >> 4, m = l & 15;

  const u16* kbase = Kp + (size_t)kvh * T_LEN * HD;
  const u16* vbase = Vtp + (size_t)kvh * HD * T_LEN;
  u16* pl = Plds + w * 512;  // per-wave P bounce [16 m][32 kv]

#define STAGE_KV(jt, b)                                                        \
  {                                                                            \
    _Pragma("unroll") for (int p = 0; p < 2; ++p) {                            \
      const int krow = p * 16 + w * 4 + (l >> 4);                              \
      const int kg = (l & 15) ^ (krow & 7);                                    \
      gll16(kbase + (size_t)((jt) * 32 + krow) * 128 + kg * 8,                 \
            Ks + (b) * 4096 + p * 2048 + w * 512 + l * 8);                     \
      const int dv = p * 64 + w * 16 + (l >> 2);                               \
      const int vg = (l & 3) ^ ((dv >> 1) & 3);                                \
      gll16(vbase + (size_t)dv * T_LEN + (jt) * 32 + vg * 8,                   \
            Vts + (b) * 4096 + p * 2048 + w * 512 + l * 8);                    \
    }                                                                          \
  }

  for (int job = 0; job < 2; ++job) {
    const int qb = job ? bx : 31 - bx;  // big first (warms KV L2 for small)
    const int t0 = qb * 64;
    const int NT = 2 * (qb + 1);

    // ---- stage Q tile (swizzle: 16B granule ^ (row&7)) ----
    {
      const u16* qbase = Qp + ((size_t)h * T_LEN + t0) * HD;
#pragma unroll
      for (int p = 0; p < 4; ++p) {
        const int row = p * 16 + w * 4 + (l >> 4);
        const int gr = (l & 15) ^ (row & 7);
        gll16(qbase + row * 128 + gr * 8, Qs + p * 2048 + w * 512 + l * 8);
      }
    }
    STAGE_KV(0, 0);
    __syncthreads();

    // ---- hoist Q B-fragments ----
    bf16x8 qf[4];
    {
      const u16* qr = Qs + (w * 16 + m) * 128;
#pragma unroll
      for (int kk = 0; kk < 4; ++kk)
        qf[kk] = *(const bf16x8*)(qr + (((kk * 4 + g) ^ (m & 7)) * 8));
    }

    f32x4 o[8];
#pragma unroll
    for (int n = 0; n < 8; ++n) o[n] = (f32x4){0.f, 0.f, 0.f, 0.f};
    float mrun = -1e30f, lrun = 0.f;

    for (int jt = 0; jt < NT; ++jt) {
      const int b = jt & 1;
      if (jt + 1 < NT) STAGE_KV(jt + 1, b ^ 1);

      // ---- S^T = K @ Q^T ----
      f32x4 s[2];
      s[0] = (f32x4){0.f, 0.f, 0.f, 0.f};
      s[1] = (f32x4){0.f, 0.f, 0.f, 0.f};
      __builtin_amdgcn_s_setprio(1);
#pragma unroll
      for (int f = 0; f < 2; ++f) {
        const u16* kr = Ks + b * 4096 + (f * 16 + m) * 128;
#pragma unroll
        for (int kk = 0; kk < 4; ++kk) {
          bf16x8 kf = *(const bf16x8*)(kr + (((kk * 4 + g) ^ (m & 7)) * 8));
          s[f] =
              __builtin_amdgcn_mfma_f32_16x16x32_bf16(kf, qf[kk], s[f], 0, 0, 0);
        }
      }
      __builtin_amdgcn_s_setprio(0);

      // ---- causal mask (only last two tiles can clip) ----
      if (jt >= NT - 2) {
        const int qg = t0 + w * 16 + m;
        const int kvb = jt * 32 + g * 4;
#pragma unroll
        for (int f = 0; f < 2; ++f)
#pragma unroll
          for (int r = 0; r < 4; ++r)
            if (kvb + f * 16 + r > qg) s[f][r] = -1e30f;
      }

      // ---- online softmax with defer-max (T13, THR=8) ----
      float pm = fmaxf(fmaxf(fmaxf(s[0][0], s[0][1]), fmaxf(s[0][2], s[0][3])),
                       fmaxf(fmaxf(s[1][0], s[1][1]), fmaxf(s[1][2], s[1][3])));
      pm = fmaxf(pm, __shfl_xor(pm, 16));
      pm = fmaxf(pm, __shfl_xor(pm, 32));
      if (!__all(pm <= mrun + 8.f)) {
        const float mn = fmaxf(mrun, pm);
        const float sc = __expf(mrun - mn);
        mrun = mn;
        lrun *= sc;
        f32x4 scr;
#pragma unroll
        for (int r = 0; r < 4; ++r) scr[r] = __shfl(sc, g * 4 + r);
#pragma unroll
        for (int n = 0; n < 8; ++n) o[n] *= scr;
      }
      float ps = 0.f;
#pragma unroll
      for (int f = 0; f < 2; ++f)
#pragma unroll
        for (int r = 0; r < 4; ++r) {
          s[f][r] = __expf(s[f][r] - mrun);
          ps += s[f][r];
        }
      ps += __shfl_xor(ps, 16);
      ps += __shfl_xor(ps, 32);
      lrun += ps;

      // ---- P -> LDS bounce (wave-private) ----
      {
        const u32 a0 = (u32)f2b(s[0][0]) | ((u32)f2b(s[0][1]) << 16);
        const u32 a1 = (u32)f2b(s[0][2]) | ((u32)f2b(s[0][3]) << 16);
        const u32 b0 = (u32)f2b(s[1][0]) | ((u32)f2b(s[1][1]) << 16);
        const u32 b1 = (u32)f2b(s[1][2]) | ((u32)f2b(s[1][3]) << 16);
        *(uint2*)(pl + m * 32 + ((g ^ (m >> 1)) * 4)) = make_uint2(a0, a1);
        *(uint2*)(pl + m * 32 + (((g + 4) ^ (m >> 1)) * 4)) = make_uint2(b0, b1);
      }

      // ---- read P A-fragment ----
      bf16x8 pa;
      {
        const uint2 lo =
            *(const uint2*)(pl + m * 32 + (((2 * g) ^ (m >> 1)) * 4));
        const uint2 hi =
            *(const uint2*)(pl + m * 32 + (((2 * g + 1) ^ (m >> 1)) * 4));
        union { u32 u[4]; bf16x8 v; } pu;
        pu.u[0] = lo.x; pu.u[1] = lo.y; pu.u[2] = hi.x; pu.u[3] = hi.y;
        pa = pu.v;
      }

      // ---- PV ----
      __builtin_amdgcn_s_setprio(1);
#pragma unroll
      for (int n = 0; n < 8; ++n) {
        const int dd = n * 16 + m;
        bf16x8 vf = *(const bf16x8*)(Vts + b * 4096 + dd * 32 +
                                     ((g ^ ((dd >> 1) & 3)) * 8));
        o[n] = __builtin_amdgcn_mfma_f32_16x16x32_bf16(pa, vf, o[n], 0, 0, 0);
      }
      __builtin_amdgcn_s_setprio(0);
      __syncthreads();
    }

    // ---- epilogue: normalize rows, write bf16 [t][h*128+d] ----
    float li[4];
#pragma unroll
    for (int r = 0; r < 4; ++r) li[r] = 1.f / __shfl(lrun, g * 4 + r);
    u16* ob = outB + (size_t)(t0 + w * 16 + g * 4) * HIDDEN + h * HD + m;
#pragma unroll
    for (int n = 0; n < 8; ++n)
#pragma unroll
      for (int r = 0; r < 4; ++r)
        ob[(size_t)r * HIDDEN + n * 16] = f2b(o[n][r] * li[r]);
  }
#undef STAGE_KV
}

// ---------------------------------------------------------------------------
extern "C" void kernel_launch(void* const* d_in, const int* in_sizes, int n_in,
                              void* d_out, int out_size, void* d_ws,
                              size_t ws_size, hipStream_t stream) {
  const float* hidden = (const float*)d_in[0];
  const int* positions = (const int*)d_in[1];
  const float* w_qkv = (const float*)d_in[2];
  const float* w_o = (const float*)d_in[3];
  const float* q_norm_w = (const float*)d_in[4];
  const float* k_norm_w = (const float*)d_in[5];
  float* out = (float*)d_out;

  // workspace layout (~176 MB); Qp aliases hiddenB (dead after GEMM1)
  u16* hiddenB = (u16*)d_ws;                                // 16.8 MB
  u16* Qp = hiddenB;                                        // alias
  u16* wqkvT = hiddenB + (size_t)T_LEN * HIDDEN;            // 50.3 MB
  u16* woT = wqkvT + (size_t)QKV_N * HIDDEN;                // 33.6 MB
  float* qkv = (float*)(woT + (size_t)HIDDEN * HIDDEN);     // 50.3 MB
  u16* attnB = (u16*)(qkv + (size_t)T_LEN * QKV_N);         // 16.8 MB
  u16* Kp = attnB + (size_t)T_LEN * HIDDEN;                 // 4.2 MB
  u16* Vtp = Kp + (size_t)N_KV * T_LEN * HD;                // 4.2 MB

  // prep
  cast_bf16_kernel<<<(T_LEN * HIDDEN) / 1024, 256, 0, stream>>>(hidden, hiddenB);
  transpose_cast_kernel<<<dim3(QKV_N / 32, HIDDEN / 32), 256, 0, stream>>>(
      w_qkv, wqkvT, HIDDEN, QKV_N);
  transpose_cast_kernel<<<dim3(HIDDEN / 32, HIDDEN / 32), 256, 0, stream>>>(
      w_o, woT, HIDDEN, HIDDEN);

  // 1) qkv = hidden @ w_qkv  (8-phase 256x256, grid 24x8)
  gemm256_kernel<256><<<dim3(QKV_N / 256, T_LEN / 256), 512, 0, stream>>>(
      hiddenB, wqkvT, qkv, T_LEN, QKV_N, HIDDEN);
  // 2) RMSNorm + RoPE -> packed bf16 Q/K; V transpose -> Vtp
  normrope_pack_kernel<<<dim3(T_LEN, N_HEADS + N_KV), 128, 0, stream>>>(
      qkv, positions, q_norm_w, k_norm_w, Qp, Kp);
  vtrans_kernel<<<dim3(T_LEN / 32, N_KV), 256, 0, stream>>>(qkv, Vtp);
  // 3) MFMA causal GQA flash attention (balanced pairing) -> bf16
  attn4_kernel<<<dim3(16, N_HEADS), 256, 0, stream>>>(Qp, Kp, Vtp, attnB);
  // 4) out = attn @ w_o  (8-phase 256x128, grid 32x8 = 256 blocks)
  gemm256_kernel<128><<<dim3(HIDDEN / 128, T_LEN / 256), 512, 0, stream>>>(
      attnB, woT, out, T_LEN, HIDDEN, HIDDEN);
}

// Round 9
// 347.994 us; speedup vs baseline: 10.9289x; 1.0511x over previous
//
#include <hip/hip_runtime.h>
#include <math.h>

#define HIDDEN 4096
#define QKV_N 6144      // (32 + 2*8) * 128
#define T_LEN 2048
#define HD 128
#define N_HEADS 32
#define N_KV 8
#define SCALE 0.08838834764831845f  // 128^-0.5

typedef unsigned short u16;
typedef unsigned int u32;
typedef __attribute__((ext_vector_type(8))) short bf16x8;
typedef __attribute__((ext_vector_type(4))) float f32x4;

// fp32 -> bf16 round-to-nearest-even
__device__ __forceinline__ u16 f2b(float x) {
  u32 u = __builtin_bit_cast(u32, x);
  u += 0x7fffu + ((u >> 16) & 1u);
  return (u16)(u >> 16);
}

typedef const __attribute__((address_space(1))) void* gas_ptr;
typedef __attribute__((address_space(3))) void* las_ptr;
__device__ __forceinline__ void gll16(const void* g, void* l) {
  __builtin_amdgcn_global_load_lds((gas_ptr)g, (las_ptr)l, 16, 0, 0);
}

// ---------------------------------------------------------------------------
// elementwise fp32 -> bf16 cast (4 elems/thread)
// ---------------------------------------------------------------------------
__global__ __launch_bounds__(256) void cast_bf16_kernel(
    const float* __restrict__ in, u16* __restrict__ out) {
  const size_t i = ((size_t)blockIdx.x * 256 + threadIdx.x) * 4;
  f32x4 v = *(const f32x4*)(in + i);
  ushort4 o;
  o.x = f2b(v[0]); o.y = f2b(v[1]); o.z = f2b(v[2]); o.w = f2b(v[3]);
  *(ushort4*)(out + i) = o;
}

// ---------------------------------------------------------------------------
// W [K][N] fp32 -> WT [N][K] bf16 (32x32 LDS tile transpose)
// ---------------------------------------------------------------------------
__global__ __launch_bounds__(256) void transpose_cast_kernel(
    const float* __restrict__ W, u16* __restrict__ WT, int K, int N) {
  __shared__ float t[32][33];
  const int n0 = blockIdx.x * 32, k0 = blockIdx.y * 32;
  const int c = threadIdx.x & 31;
  const int r0 = threadIdx.x >> 5;
#pragma unroll
  for (int j = 0; j < 4; ++j) {
    const int r = r0 + 8 * j;
    t[c][r] = W[(size_t)(k0 + r) * N + n0 + c];
  }
  __syncthreads();
#pragma unroll
  for (int j = 0; j < 4; ++j) {
    const int n = r0 + 8 * j;
    WT[(size_t)(n0 + n) * K + k0 + c] = f2b(t[n][c]);
  }
}

// ---------------------------------------------------------------------------
// 2-stretch 256xBN bf16 MFMA GEMM. BM=256, BK=64, 512 thr (8 waves 2Mx4N).
// Per K-tile: 2 stretches (one per k-half kh). Each stretch: 12 ds_read_b128
// + stage-next-unit (gll16) + 32 MFMA, then counted vmcnt + ONE s_barrier.
// Minimal-barrier derivation: reads of buf b never alias gll-writes to b^1,
// and staging overwrite of a region is always >= 2 barriers after its last
// read (read at stretch s completes before s's barrier; overwrite at s+2).
// vmcnt: stretch0 of tile t lands kh1(t); stretch1 lands kh0(t+1).
// LDS k-split planes [buf][kh][rows][32]; octet swizzle o ^= (r>>1)&3 on
// both stage-source and ds_read (involution, rule #21) -> 0 bank conflicts.
// ---------------------------------------------------------------------------
template <int BN>
__global__ __launch_bounds__(512, 2) void gemm256_kernel(
    const u16* __restrict__ A, const u16* __restrict__ BT,
    float* __restrict__ C, int M, int N, int K) {
  constexpr int WCOLS = BN / 4;     // 64 or 32
  constexpr int NF = WCOLS / 16;    // 4 or 2  (N-frags per wave)
  constexpr int BLOADS = BN / 128;  // 2 or 1  (gll16 per B unit per thread)
  __shared__ __align__(16) u16 As[2][2][256 * 32];
  __shared__ __align__(16) u16 Bs[2][2][BN * 32];

  const int tid = threadIdx.x;
  const int w = tid >> 6, l = tid & 63;
  const int wr = w >> 2, wc = w & 3;
  const int m = l & 15, g = l >> 4;
  const int bm = blockIdx.y * 256, bn = blockIdx.x * BN;
  const int NT = K >> 6;

  size_t gA[2]; int sA[2];
  size_t gB[2]; int sB[2];
#pragma unroll
  for (int i = 0; i < 2; ++i) {
    const int s = i * 512 + tid;
    const int r = s >> 2, o = s & 3;
    sA[i] = s * 8;
    gA[i] = (size_t)(bm + r) * K + (o ^ ((r >> 1) & 3)) * 8;
  }
#pragma unroll
  for (int i = 0; i < BLOADS; ++i) {
    const int s = i * 512 + tid;
    const int r = s >> 2, o = s & 3;
    sB[i] = s * 8;
    gB[i] = (size_t)(bn + r) * K + (o ^ ((r >> 1) & 3)) * 8;
  }

  const int foff = m * 32 + ((g ^ ((m >> 1) & 3)) * 8);
  const int abase = wr * 128 * 32;
  const int bbase = wc * WCOLS * 32;

#define STAGE_A(tile, kh)                                                      \
  {                                                                            \
    const size_t kofs = (size_t)(tile) * 64 + (kh) * 32;                       \
    u16* dst = &As[(tile) & 1][kh][0];                                         \
    gll16(A + gA[0] + kofs, dst + sA[0]);                                      \
    gll16(A + gA[1] + kofs, dst + sA[1]);                                      \
  }
#define STAGE_B(tile, kh)                                                      \
  {                                                                            \
    const size_t kofs = (size_t)(tile) * 64 + (kh) * 32;                       \
    u16* dst = &Bs[(tile) & 1][kh][0];                                         \
    gll16(BT + gB[0] + kofs, dst + sB[0]);                                     \
    if constexpr (BLOADS > 1) gll16(BT + gB[1] + kofs, dst + sB[1]);           \
  }
#define VM_COUNTED()                                                           \
  {                                                                            \
    if constexpr (BN == 256)                                                   \
      asm volatile("s_waitcnt vmcnt(4)" ::: "memory");                         \
    else                                                                       \
      asm volatile("s_waitcnt vmcnt(3)" ::: "memory");                         \
  }
// One stretch: full k-half kh of buf b. 12 (10) ds_read_b128, 32 (16) MFMA.
// VM: 0 = vmcnt(0)+barrier, 1 = counted+barrier, 2 = none (kernel tail).
#define STRETCH(kh, b, DO_STAGE, tn, VM)                                       \
  {                                                                            \
    bf16x8 af[8];                                                              \
    _Pragma("unroll") for (int fm = 0; fm < 8; ++fm)                           \
        af[fm] = *(const bf16x8*)(&As[b][kh][abase + fm * 512 + foff]);        \
    bf16x8 bf[NF];                                                             \
    _Pragma("unroll") for (int fn = 0; fn < NF; ++fn)                          \
        bf[fn] = *(const bf16x8*)(&Bs[b][kh][bbase + fn * 512 + foff]);        \
    if constexpr (DO_STAGE) { STAGE_A(tn, kh); STAGE_B(tn, kh); }              \
    __builtin_amdgcn_s_setprio(1);                                             \
    _Pragma("unroll") for (int fm = 0; fm < 8; ++fm)                           \
        _Pragma("unroll") for (int fn = 0; fn < NF; ++fn)                      \
        acc[fm][fn] = __builtin_amdgcn_mfma_f32_16x16x32_bf16(                 \
            af[fm], bf[fn], acc[fm][fn], 0, 0, 0);                             \
    __builtin_amdgcn_s_setprio(0);                                             \
    asm volatile("" ::: "memory");                                             \
    if constexpr ((VM) == 0) asm volatile("s_waitcnt vmcnt(0)" ::: "memory");  \
    if constexpr ((VM) == 1) VM_COUNTED();                                     \
    if constexpr ((VM) != 2) {                                                 \
      __builtin_amdgcn_s_barrier();                                            \
      asm volatile("" ::: "memory");                                           \
    }                                                                          \
  }

  f32x4 acc[8][NF];
#pragma unroll
  for (int i = 0; i < 8; ++i)
#pragma unroll
    for (int j = 0; j < NF; ++j) acc[i][j] = (f32x4){0.f, 0.f, 0.f, 0.f};

  // prologue: stage tile 0 fully; land kh0 (leave kh1 in flight)
  STAGE_A(0, 0); STAGE_B(0, 0); STAGE_A(0, 1); STAGE_B(0, 1);
  VM_COUNTED();
  __builtin_amdgcn_s_barrier();
  asm volatile("" ::: "memory");

  for (int t = 0; t < NT - 1; ++t) {
    const int b = t & 1, tn = t + 1;
    STRETCH(0, b, true, tn, 1);  // lands kh1 of tile t
    STRETCH(1, b, true, tn, 1);  // lands kh0 of tile t+1
  }
  {  // tail K-tile: no staging
    const int b = (NT - 1) & 1;
    STRETCH(0, b, false, 0, 0);  // drain kh1 of tail tile
    STRETCH(1, b, false, 0, 2);  // last compute, no sync
  }
#undef STRETCH
#undef VM_COUNTED
#undef STAGE_B
#undef STAGE_A

  // C/D layout (verified r5): row = base + g*4 + r, col = base + m
#pragma unroll
  for (int fm = 0; fm < 8; ++fm) {
    const int row = bm + wr * 128 + fm * 16 + g * 4;
#pragma unroll
    for (int fn = 0; fn < NF; ++fn) {
      const int col = bn + wc * WCOLS + fn * 16 + m;
      float* cp = C + (size_t)row * N + col;
#pragma unroll
      for (int r = 0; r < 4; ++r) cp[(size_t)r * N] = acc[fm][fn][r];
    }
  }
}

// ---------------------------------------------------------------------------
// Fused per-head RMSNorm + partial RoPE -> packed bf16.
// ---------------------------------------------------------------------------
__global__ __launch_bounds__(128) void normrope_pack_kernel(
    const float* __restrict__ qkv, const int* __restrict__ positions,
    const float* __restrict__ qw, const float* __restrict__ kw,
    u16* __restrict__ Qp, u16* __restrict__ Kp) {
  const int t = blockIdx.x;
  const int hh = blockIdx.y;  // 0..39
  const int d = threadIdx.x;  // 0..127
  const bool isq = hh < N_HEADS;
  const int col = isq ? hh * HD : HIDDEN + (hh - N_HEADS) * HD;
  const float* row = qkv + (size_t)t * QKV_N + col;
  const float* w = isq ? qw : kw;

  float x = row[d];
  float ss = x * x;
#pragma unroll
  for (int off = 32; off >= 1; off >>= 1) ss += __shfl_xor(ss, off);
  __shared__ float wsum[2];
  __shared__ float xs[128];
  if ((d & 63) == 0) wsum[d >> 6] = ss;
  __syncthreads();
  const float tot = wsum[0] + wsum[1];
  const float inv = rsqrtf(tot * (1.f / 128.f) + 1e-6f);
  const float xn = x * inv * w[d];
  xs[d] = xn;
  __syncthreads();

  float outv;
  if (d < 64) {
    const int idx = d & 31;
    const float invf = powf(1.0e6f, -(float)idx * (1.0f / 32.0f));
    const float fr = (float)positions[t] * invf;
    const float c = cosf(fr), s = sinf(fr);
    const float x1 = xs[idx], x2 = xs[idx + 32];
    outv = (d < 32) ? (x1 * c - x2 * s) : (x2 * c + x1 * s);
  } else {
    outv = xn;
  }
  if (isq) {
    Qp[((size_t)hh * T_LEN + t) * HD + d] = f2b(outv * SCALE);
  } else {
    Kp[((size_t)(hh - N_HEADS) * T_LEN + t) * HD + d] = f2b(outv);
  }
}

// ---------------------------------------------------------------------------
// V transpose+cast: qkv V region fp32 [t][d] -> Vtp[kvh][d][t] bf16.
// ---------------------------------------------------------------------------
__global__ __launch_bounds__(256) void vtrans_kernel(
    const float* __restrict__ qkv, u16* __restrict__ Vtp) {
  __shared__ float tile[32][132];
  const int t0 = blockIdx.x * 32;
  const int kvh = blockIdx.y;
  const int tv = threadIdx.x >> 3;          // 0..31
  const int c0 = (threadIdx.x & 7) * 16;    // 0..112
  const float* src =
      qkv + (size_t)(t0 + tv) * QKV_N + (HIDDEN + 1024) + kvh * HD + c0;
#pragma unroll
  for (int u = 0; u < 4; ++u)
    *(f32x4*)&tile[tv][c0 + 4 * u] = *(const f32x4*)(src + 4 * u);
  __syncthreads();
  const int dd = threadIdx.x >> 1;   // 0..127
  const int half = threadIdx.x & 1;  // 0,1
  u16 buf[16];
#pragma unroll
  for (int p = 0; p < 16; ++p) buf[p] = f2b(tile[half * 16 + p][dd]);
  u16* dst = Vtp + ((size_t)kvh * HD + dd) * T_LEN + t0 + half * 16;
  *(uint4*)dst = *(uint4*)&buf[0];
  *(uint4*)(dst + 8) = *(uint4*)&buf[8];
}

// ---------------------------------------------------------------------------
// MFMA causal GQA flash attention, work-balanced pairing + defer-max + T5.
// grid (16, 32): block bx handles Q-tiles qb = 31-bx then bx (NT sum = 66
// KV-tiles = constant -> no load-imbalance tail). 256 thr (4 waves).
// ---------------------------------------------------------------------------
__global__ __launch_bounds__(256, 3) void attn4_kernel(
    const u16* __restrict__ Qp, const u16* __restrict__ Kp,
    const u16* __restrict__ Vtp, u16* __restrict__ outB) {
  __shared__ __align__(16) u16 Qs[64 * 128];
  __shared__ __align__(16) u16 Ks[2 * 32 * 128];
  __shared__ __align__(16) u16 Vts[2 * 128 * 32];
  __shared__ __align__(16) u16 Plds[4 * 16 * 32];

  const int bx = blockIdx.x;  // 0..15
  const int h = blockIdx.y;
  const int kvh = h >> 2;
  const int tid = threadIdx.x;
  const int w = tid >> 6, l = tid & 63;
  const int g = l >> 4, m = l & 15;

  const u16* kbase = Kp + (size_t)kvh * T_LEN * HD;
  const u16* vbase = Vtp + (size_t)kvh * HD * T_LEN;
  u16* pl = Plds + w * 512;  // per-wave P bounce [16 m][32 kv]

#define STAGE_KV(jt, b)                                                        \
  {                                                                            \
    _Pragma("unroll") for (int p = 0; p < 2; ++p) {                            \
      const int krow = p * 16 + w * 4 + (l >> 4);                              \
      const int kg = (l & 15) ^ (krow & 7);                                    \
      gll16(kbase + (size_t)((jt) * 32 + krow) * 128 + kg * 8,                 \
            Ks + (b) * 4096 + p * 2048 + w * 512 + l * 8);                     \
      const int dv = p * 64 + w * 16 + (l >> 2);                               \
      const int vg = (l & 3) ^ ((dv >> 1) & 3);                                \
      gll16(vbase + (size_t)dv * T_LEN + (jt) * 32 + vg * 8,                   \
            Vts + (b) * 4096 + p * 2048 + w * 512 + l * 8);                    \
    }                                                                          \
  }

  for (int job = 0; job < 2; ++job) {
    const int qb = job ? bx : 31 - bx;  // big first (warms KV L2 for small)
    const int t0 = qb * 64;
    const int NT = 2 * (qb + 1);

    // ---- stage Q tile (swizzle: 16B granule ^ (row&7)) ----
    {
      const u16* qbase = Qp + ((size_t)h * T_LEN + t0) * HD;
#pragma unroll
      for (int p = 0; p < 4; ++p) {
        const int row = p * 16 + w * 4 + (l >> 4);
        const int gr = (l & 15) ^ (row & 7);
        gll16(qbase + row * 128 + gr * 8, Qs + p * 2048 + w * 512 + l * 8);
      }
    }
    STAGE_KV(0, 0);
    __syncthreads();

    // ---- hoist Q B-fragments ----
    bf16x8 qf[4];
    {
      const u16* qr = Qs + (w * 16 + m) * 128;
#pragma unroll
      for (int kk = 0; kk < 4; ++kk)
        qf[kk] = *(const bf16x8*)(qr + (((kk * 4 + g) ^ (m & 7)) * 8));
    }

    f32x4 o[8];
#pragma unroll
    for (int n = 0; n < 8; ++n) o[n] = (f32x4){0.f, 0.f, 0.f, 0.f};
    float mrun = -1e30f, lrun = 0.f;

    for (int jt = 0; jt < NT; ++jt) {
      const int b = jt & 1;
      if (jt + 1 < NT) STAGE_KV(jt + 1, b ^ 1);

      // ---- S^T = K @ Q^T ----
      f32x4 s[2];
      s[0] = (f32x4){0.f, 0.f, 0.f, 0.f};
      s[1] = (f32x4){0.f, 0.f, 0.f, 0.f};
      __builtin_amdgcn_s_setprio(1);
#pragma unroll
      for (int f = 0; f < 2; ++f) {
        const u16* kr = Ks + b * 4096 + (f * 16 + m) * 128;
#pragma unroll
        for (int kk = 0; kk < 4; ++kk) {
          bf16x8 kf = *(const bf16x8*)(kr + (((kk * 4 + g) ^ (m & 7)) * 8));
          s[f] =
              __builtin_amdgcn_mfma_f32_16x16x32_bf16(kf, qf[kk], s[f], 0, 0, 0);
        }
      }
      __builtin_amdgcn_s_setprio(0);

      // ---- causal mask (only last two tiles can clip) ----
      if (jt >= NT - 2) {
        const int qg = t0 + w * 16 + m;
        const int kvb = jt * 32 + g * 4;
#pragma unroll
        for (int f = 0; f < 2; ++f)
#pragma unroll
          for (int r = 0; r < 4; ++r)
            if (kvb + f * 16 + r > qg) s[f][r] = -1e30f;
      }

      // ---- online softmax with defer-max (T13, THR=8) ----
      float pm = fmaxf(fmaxf(fmaxf(s[0][0], s[0][1]), fmaxf(s[0][2], s[0][3])),
                       fmaxf(fmaxf(s[1][0], s[1][1]), fmaxf(s[1][2], s[1][3])));
      pm = fmaxf(pm, __shfl_xor(pm, 16));
      pm = fmaxf(pm, __shfl_xor(pm, 32));
      if (!__all(pm <= mrun + 8.f)) {
        const float mn = fmaxf(mrun, pm);
        const float sc = __expf(mrun - mn);
        mrun = mn;
        lrun *= sc;
        f32x4 scr;
#pragma unroll
        for (int r = 0; r < 4; ++r) scr[r] = __shfl(sc, g * 4 + r);
#pragma unroll
        for (int n = 0; n < 8; ++n) o[n] *= scr;
      }
      float ps = 0.f;
#pragma unroll
      for (int f = 0; f < 2; ++f)
#pragma unroll
        for (int r = 0; r < 4; ++r) {
          s[f][r] = __expf(s[f][r] - mrun);
          ps += s[f][r];
        }
      ps += __shfl_xor(ps, 16);
      ps += __shfl_xor(ps, 32);
      lrun += ps;

      // ---- P -> LDS bounce (wave-private) ----
      {
        const u32 a0 = (u32)f2b(s[0][0]) | ((u32)f2b(s[0][1]) << 16);
        const u32 a1 = (u32)f2b(s[0][2]) | ((u32)f2b(s[0][3]) << 16);
        const u32 b0 = (u32)f2b(s[1][0]) | ((u32)f2b(s[1][1]) << 16);
        const u32 b1 = (u32)f2b(s[1][2]) | ((u32)f2b(s[1][3]) << 16);
        *(uint2*)(pl + m * 32 + ((g ^ (m >> 1)) * 4)) = make_uint2(a0, a1);
        *(uint2*)(pl + m * 32 + (((g + 4) ^ (m >> 1)) * 4)) = make_uint2(b0, b1);
      }

      // ---- read P A-fragment ----
      bf16x8 pa;
      {
        const uint2 lo =
            *(const uint2*)(pl + m * 32 + (((2 * g) ^ (m >> 1)) * 4));
        const uint2 hi =
            *(const uint2*)(pl + m * 32 + (((2 * g + 1) ^ (m >> 1)) * 4));
        union { u32 u[4]; bf16x8 v; } pu;
        pu.u[0] = lo.x; pu.u[1] = lo.y; pu.u[2] = hi.x; pu.u[3] = hi.y;
        pa = pu.v;
      }

      // ---- PV ----
      __builtin_amdgcn_s_setprio(1);
#pragma unroll
      for (int n = 0; n < 8; ++n) {
        const int dd = n * 16 + m;
        bf16x8 vf = *(const bf16x8*)(Vts + b * 4096 + dd * 32 +
                                     ((g ^ ((dd >> 1) & 3)) * 8));
        o[n] = __builtin_amdgcn_mfma_f32_16x16x32_bf16(pa, vf, o[n], 0, 0, 0);
      }
      __builtin_amdgcn_s_setprio(0);
      __syncthreads();
    }

    // ---- epilogue: normalize rows, write bf16 [t][h*128+d] ----
    float li[4];
#pragma unroll
    for (int r = 0; r < 4; ++r) li[r] = 1.f / __shfl(lrun, g * 4 + r);
    u16* ob = outB + (size_t)(t0 + w * 16 + g * 4) * HIDDEN + h * HD + m;
#pragma unroll
    for (int n = 0; n < 8; ++n)
#pragma unroll
      for (int r = 0; r < 4; ++r)
        ob[(size_t)r * HIDDEN + n * 16] = f2b(o[n][r] * li[r]);
  }
#undef STAGE_KV
}

// ---------------------------------------------------------------------------
extern "C" void kernel_launch(void* const* d_in, const int* in_sizes, int n_in,
                              void* d_out, int out_size, void* d_ws,
                              size_t ws_size, hipStream_t stream) {
  const float* hidden = (const float*)d_in[0];
  const int* positions = (const int*)d_in[1];
  const float* w_qkv = (const float*)d_in[2];
  const float* w_o = (const float*)d_in[3];
  const float* q_norm_w = (const float*)d_in[4];
  const float* k_norm_w = (const float*)d_in[5];
  float* out = (float*)d_out;

  // workspace layout (~176 MB); Qp aliases hiddenB (dead after GEMM1)
  u16* hiddenB = (u16*)d_ws;                                // 16.8 MB
  u16* Qp = hiddenB;                                        // alias
  u16* wqkvT = hiddenB + (size_t)T_LEN * HIDDEN;            // 50.3 MB
  u16* woT = wqkvT + (size_t)QKV_N * HIDDEN;                // 33.6 MB
  float* qkv = (float*)(woT + (size_t)HIDDEN * HIDDEN);     // 50.3 MB
  u16* attnB = (u16*)(qkv + (size_t)T_LEN * QKV_N);         // 16.8 MB
  u16* Kp = attnB + (size_t)T_LEN * HIDDEN;                 // 4.2 MB
  u16* Vtp = Kp + (size_t)N_KV * T_LEN * HD;                // 4.2 MB

  // prep
  cast_bf16_kernel<<<(T_LEN * HIDDEN) / 1024, 256, 0, stream>>>(hidden, hiddenB);
  transpose_cast_kernel<<<dim3(QKV_N / 32, HIDDEN / 32), 256, 0, stream>>>(
      w_qkv, wqkvT, HIDDEN, QKV_N);
  transpose_cast_kernel<<<dim3(HIDDEN / 32, HIDDEN / 32), 256, 0, stream>>>(
      w_o, woT, HIDDEN, HIDDEN);

  // 1) qkv = hidden @ w_qkv  (2-stretch 256x256, grid 24x8)
  gemm256_kernel<256><<<dim3(QKV_N / 256, T_LEN / 256), 512, 0, stream>>>(
      hiddenB, wqkvT, qkv, T_LEN, QKV_N, HIDDEN);
  // 2) RMSNorm + RoPE -> packed bf16 Q/K; V transpose -> Vtp
  normrope_pack_kernel<<<dim3(T_LEN, N_HEADS + N_KV), 128, 0, stream>>>(
      qkv, positions, q_norm_w, k_norm_w, Qp, Kp);
  vtrans_kernel<<<dim3(T_LEN / 32, N_KV), 256, 0, stream>>>(qkv, Vtp);
  // 3) MFMA causal GQA flash attention (balanced pairing) -> bf16
  attn4_kernel<<<dim3(16, N_HEADS), 256, 0, stream>>>(Qp, Kp, Vtp, attnB);
  // 4) out = attn @ w_o  (2-stretch 256x128, grid 32x8 = 256 blocks)
  gemm256_kernel<128><<<dim3(HIDDEN / 128, T_LEN / 256), 512, 0, stream>>>(
      attnB, woT, out, T_LEN, HIDDEN, HIDDEN);
}